// Round 1
// baseline (753.105 us; speedup 1.0000x reference)
//
#include <hip/hip_runtime.h>

typedef __attribute__((ext_vector_type(4))) float f32x4;
typedef __attribute__((ext_vector_type(4))) unsigned int u32x4;
typedef __attribute__((ext_vector_type(8))) short short8;
typedef __attribute__((ext_vector_type(4))) unsigned short u16x4;

#define DEV static __device__ __forceinline__

DEV unsigned short f2bf(float f) {
  union { float f; unsigned u; } v; v.f = f;
  unsigned r = v.u + 0x7fffu + ((v.u >> 16) & 1u);
  return (unsigned short)(r >> 16);
}
DEV float bf2f(unsigned short s) {
  union { unsigned u; float f; } v; v.u = ((unsigned)s) << 16;
  return v.f;
}

constexpr int KS = 32;   // K-step
constexpr int LR = 40;   // LDS row: 32 + 8 pad -> 80B rows, 16B aligned, ~2-way banks

// ---------------------------------------------------------------------------
// Generic bf16 MFMA GEMM: C[M,N] = act( bf16(A) * bf16(B) + bias )
// A: f32 (with optional row gather) or bf16, row index = gidx[m] or m*rmul+radd
// B: f32 [K][N] row-major, converted+transposed into LDS
// OUTM: bit0 -> f32 out, bit1 -> bf16 out
// ---------------------------------------------------------------------------
template<int BM, int BN, bool ABF16, bool GATHER, bool RELU, int OUTM>
__global__ __launch_bounds__(256)
void gemm_k(const void* __restrict__ Av, int lda, int rmul, int radd,
            const int* __restrict__ gidx,
            const float* __restrict__ Bp, int ldb,
            const float* __restrict__ bias,
            float* __restrict__ Cf, unsigned short* __restrict__ Cb, int ldc,
            int M, int N, int K)
{
  constexpr int WM = BM / 2, WN = BN / 2, FM = WM / 16, FN = WN / 16;
  __shared__ unsigned short As[2][BM][LR];
  __shared__ unsigned short Bs[2][BN][LR];
  const int tid = threadIdx.x;
  const int lane = tid & 63;
  const int wid = tid >> 6;
  const int wy = wid >> 1, wx = wid & 1;
  const long m0 = (long)blockIdx.x * BM;
  const int n0 = blockIdx.y * BN;

  f32x4 acc[FM][FN];
#pragma unroll
  for (int i = 0; i < FM; ++i)
#pragma unroll
    for (int j = 0; j < FN; ++j) acc[i][j] = (f32x4)0.f;

  const int nsteps = K / KS;

  auto stageA = [&](int ks, int buf) {
    const int k0 = ks * KS;
    if constexpr (!ABF16) {
      const float* A = (const float*)Av;
#pragma unroll
      for (int p = 0; p < BM / 32; ++p) {
        const int r = p * 32 + (tid >> 3);
        const int kq = tid & 7;
        long ar = GATHER ? (long)gidx[m0 + r] : ((m0 + r) * (long)rmul + radd);
        f32x4 v = *(const f32x4*)(A + ar * lda + k0 + kq * 4);
        u16x4 o;
        o[0] = f2bf(v[0]); o[1] = f2bf(v[1]); o[2] = f2bf(v[2]); o[3] = f2bf(v[3]);
        *(u16x4*)(&As[buf][r][kq * 4]) = o;
      }
    } else {
      const unsigned short* A = (const unsigned short*)Av;
#pragma unroll
      for (int p = 0; p < BM / 64; ++p) {
        const int r = p * 64 + (tid >> 2);
        const int cq = tid & 3;
        long ar = (m0 + r) * (long)rmul + radd;
        u32x4 v = *(const u32x4*)(A + ar * lda + k0 + cq * 8);
        *(u32x4*)(&As[buf][r][cq * 8]) = v;
      }
    }
  };

  auto stageB = [&](int ks, int buf) {
    const int k0 = ks * KS;
    constexpr int NC = BN / 4;
#pragma unroll
    for (int p = 0; p < (KS * NC) / 256; ++p) {
      const int n4 = tid % NC;
      const int k = p * (256 / NC) + tid / NC;
      const int c0 = n0 + n4 * 4;
      f32x4 v;
      if (c0 + 3 < N) {
        v = *(const f32x4*)(Bp + (long)(k0 + k) * ldb + c0);
      } else {
#pragma unroll
        for (int e = 0; e < 4; ++e)
          v[e] = (c0 + e < N) ? Bp[(long)(k0 + k) * ldb + c0 + e] : 0.f;
      }
      Bs[buf][n4 * 4 + 0][k] = f2bf(v[0]);
      Bs[buf][n4 * 4 + 1][k] = f2bf(v[1]);
      Bs[buf][n4 * 4 + 2][k] = f2bf(v[2]);
      Bs[buf][n4 * 4 + 3][k] = f2bf(v[3]);
    }
  };

  stageA(0, 0); stageB(0, 0);

  for (int ks = 0; ks < nsteps; ++ks) {
    __syncthreads();
    if (ks + 1 < nsteps) { stageA(ks + 1, (ks + 1) & 1); stageB(ks + 1, (ks + 1) & 1); }
    const int buf = ks & 1;
    short8 ar[FM], br[FN];
#pragma unroll
    for (int fm = 0; fm < FM; ++fm)
      ar[fm] = *(const short8*)(&As[buf][wy * WM + fm * 16 + (lane & 15)][(lane >> 4) * 8]);
#pragma unroll
    for (int fn = 0; fn < FN; ++fn)
      br[fn] = *(const short8*)(&Bs[buf][wx * WN + fn * 16 + (lane & 15)][(lane >> 4) * 8]);
#pragma unroll
    for (int fm = 0; fm < FM; ++fm)
#pragma unroll
      for (int fn = 0; fn < FN; ++fn)
        acc[fm][fn] = __builtin_amdgcn_mfma_f32_16x16x32_bf16(ar[fm], br[fn], acc[fm][fn], 0, 0, 0);
  }

#pragma unroll
  for (int fm = 0; fm < FM; ++fm) {
    const long row0 = m0 + wy * WM + fm * 16 + ((lane >> 4) << 2);
#pragma unroll
    for (int fn = 0; fn < FN; ++fn) {
      const int col = n0 + wx * WN + fn * 16 + (lane & 15);
      if (col >= N) continue;
      const float bv = bias ? bias[col] : 0.f;
#pragma unroll
      for (int j = 0; j < 4; ++j) {
        float v = acc[fm][fn][j] + bv;
        if constexpr (RELU) v = fmaxf(v, 0.f);
        const long r = row0 + j;
        if constexpr (OUTM & 1) Cf[r * ldc + col] = v;
        if constexpr (OUTM & 2) Cb[r * ldc + col] = f2bf(v);
      }
    }
  }
}

// ---------------------------------------------------------------------------
// Fused alpha kernel: for tile of 64 (b,l) rows and one head n:
//   q2 = fea @ w2_w[n]  (MFMA, K=256), then
//   alpha[b,n,l] = sum_d sigmoid(q2 + q1buf[b,n,d]) * v_w[n,d]
// q1buf already contains ht@w1_w + w1_b + w2_b.
// ---------------------------------------------------------------------------
__global__ __launch_bounds__(256)
void alpha_k(const unsigned short* __restrict__ fea,   // [25600][256] bf16
             const unsigned short* __restrict__ w2t,   // [8][256(d)][256(h)] bf16
             const float* __restrict__ q1buf,          // [512][2048]
             const float* __restrict__ vw,             // [8][256]
             float* __restrict__ alpha)                // [512][8][50]
{
  __shared__ unsigned short As[2][64][LR];
  __shared__ unsigned short Bs[2][256][LR];
  __shared__ float vws[256];
  __shared__ float red[4][64];
  const int tid = threadIdx.x;
  const int lane = tid & 63;
  const int w = tid >> 6;
  const int m0 = blockIdx.x * 64;
  const int n = blockIdx.y;

  vws[tid] = vw[n * 256 + tid];

  f32x4 acc[4][4];
#pragma unroll
  for (int i = 0; i < 4; ++i)
#pragma unroll
    for (int j = 0; j < 4; ++j) acc[i][j] = (f32x4)0.f;

  auto stageA = [&](int ks, int buf) {
    const int k0 = ks * KS;
    const int r = tid >> 2, cq = tid & 3;
    u32x4 v = *(const u32x4*)(fea + (long)(m0 + r) * 256 + k0 + cq * 8);
    *(u32x4*)(&As[buf][r][cq * 8]) = v;
  };
  auto stageB = [&](int ks, int buf) {
    const int k0 = ks * KS;
#pragma unroll
    for (int p = 0; p < 4; ++p) {
      const int r = p * 64 + (tid >> 2), cq = tid & 3;
      u32x4 v = *(const u32x4*)(w2t + ((long)(n * 256 + r)) * 256 + k0 + cq * 8);
      *(u32x4*)(&Bs[buf][r][cq * 8]) = v;
    }
  };

  stageA(0, 0); stageB(0, 0);
  for (int ks = 0; ks < 8; ++ks) {
    __syncthreads();
    if (ks < 7) { stageA(ks + 1, (ks + 1) & 1); stageB(ks + 1, (ks + 1) & 1); }
    const int buf = ks & 1;
    short8 ar[4], br[4];
#pragma unroll
    for (int fm = 0; fm < 4; ++fm)
      ar[fm] = *(const short8*)(&As[buf][fm * 16 + (lane & 15)][(lane >> 4) * 8]);
#pragma unroll
    for (int fn = 0; fn < 4; ++fn)
      br[fn] = *(const short8*)(&Bs[buf][w * 64 + fn * 16 + (lane & 15)][(lane >> 4) * 8]);
#pragma unroll
    for (int fm = 0; fm < 4; ++fm)
#pragma unroll
      for (int fn = 0; fn < 4; ++fn)
        acc[fm][fn] = __builtin_amdgcn_mfma_f32_16x16x32_bf16(ar[fm], br[fn], acc[fm][fn], 0, 0, 0);
  }

  // epilogue: sigmoid + dot v_w, reduce over 256 cols
  const int g = lane >> 4, c = lane & 15;
  float part[4][4];
#pragma unroll
  for (int fm = 0; fm < 4; ++fm) {
#pragma unroll
    for (int j = 0; j < 4; ++j) {
      const int m = m0 + fm * 16 + g * 4 + j;
      const int b = m / 50;
      float p = 0.f;
#pragma unroll
      for (int fn = 0; fn < 4; ++fn) {
        const int col = w * 64 + fn * 16 + c;
        const float q = acc[fm][fn][j] + q1buf[(long)b * 2048 + n * 256 + col];
        const float s = 1.f / (1.f + __expf(-q));
        p += s * vws[col];
      }
      part[fm][j] = p;
    }
  }
#pragma unroll
  for (int fm = 0; fm < 4; ++fm)
#pragma unroll
    for (int j = 0; j < 4; ++j)
#pragma unroll
      for (int off = 1; off < 16; off <<= 1)
        part[fm][j] += __shfl_xor(part[fm][j], off);
  if (c == 0) {
#pragma unroll
    for (int fm = 0; fm < 4; ++fm)
#pragma unroll
      for (int j = 0; j < 4; ++j)
        red[w][fm * 16 + g * 4 + j] = part[fm][j];
  }
  __syncthreads();
  if (tid < 64) {
    const float s = red[0][tid] + red[1][tid] + red[2][tid] + red[3][tid];
    const int m = m0 + tid;
    const int b = m / 50, l = m - b * 50;
    alpha[((long)b * 8 + n) * 50 + l] = s;
  }
}

// ---------------------------------------------------------------------------
// c_final: per b, a[b,n,h] = sum_l alpha*mask*fea; layout [b][n*512 + {a|ht}]
// ---------------------------------------------------------------------------
__global__ __launch_bounds__(256)
void cfinal_k(const unsigned short* __restrict__ fea,
              const float* __restrict__ alpha,
              const int* __restrict__ seq,
              unsigned short* __restrict__ cfin)
{
  __shared__ unsigned short feas[50][256];
  __shared__ float al[8][50];
  const int b = blockIdx.x, t = threadIdx.x;
#pragma unroll 1
  for (int l = 0; l < 50; ++l)
    feas[l][t] = fea[((long)b * 50 + l) * 256 + t];
  for (int i = t; i < 400; i += 256) {
    const int nn = i / 50, l = i - nn * 50;
    const float mk = (seq[b * 50 + l] > 0) ? 1.f : 0.f;
    al[nn][l] = alpha[((long)b * 8 + nn) * 50 + l] * mk;
  }
  __syncthreads();
  const unsigned short htv = feas[49][t];
#pragma unroll 1
  for (int nn = 0; nn < 8; ++nn) {
    float acc = 0.f;
#pragma unroll
    for (int l = 0; l < 50; ++l) acc += al[nn][l] * bf2f(feas[l][t]);
    cfin[(long)b * 4096 + nn * 512 + t] = f2bf(acc);
    cfin[(long)b * 4096 + nn * 512 + 256 + t] = htv;
  }
}

// ---------------------------------------------------------------------------
// BatchNorm stats over batch (512 rows) per column (256 cols)
// ---------------------------------------------------------------------------
__global__ __launch_bounds__(256)
void bnstat_k(const float* __restrict__ y, float* __restrict__ mean, float* __restrict__ rstd)
{
  const int t = threadIdx.x;
  const int col = blockIdx.x * 8 + (t & 7);
  const int rg = t >> 3;
  float s = 0.f, q = 0.f;
#pragma unroll
  for (int i = 0; i < 16; ++i) {
    const float v = y[(rg + i * 32) * 256 + col];
    s += v; q += v * v;
  }
  for (int off = 8; off < 64; off <<= 1) { s += __shfl_xor(s, off); q += __shfl_xor(q, off); }
  __shared__ float ps[4][8], pq[4][8];
  if ((t & 63) < 8) { ps[t >> 6][t & 7] = s; pq[t >> 6][t & 7] = q; }
  __syncthreads();
  if (t < 8) {
    const float S = ps[0][t] + ps[1][t] + ps[2][t] + ps[3][t];
    const float Q = pq[0][t] + pq[1][t] + pq[2][t] + pq[3][t];
    const float m = S * (1.f / 512.f);
    const float v = Q * (1.f / 512.f) - m * m;
    mean[blockIdx.x * 8 + t] = m;
    rstd[blockIdx.x * 8 + t] = rsqrtf(v + 1e-5f);
  }
}

template<bool LAST>
__global__ __launch_bounds__(256)
void bnapply_k(const float* __restrict__ y, const float* __restrict__ mean,
               const float* __restrict__ rstd, const float* __restrict__ g,
               const float* __restrict__ be, const float* __restrict__ cres,
               unsigned short* __restrict__ out)
{
  const int i = (blockIdx.x * 256 + threadIdx.x) * 4;
  const int col = i & 255;
  f32x4 yv = *(const f32x4*)(y + i);
  f32x4 mv = *(const f32x4*)(mean + col);
  f32x4 rv = *(const f32x4*)(rstd + col);
  f32x4 gv = *(const f32x4*)(g + col);
  f32x4 bv = *(const f32x4*)(be + col);
  u16x4 o;
#pragma unroll
  for (int e = 0; e < 4; ++e) {
    float h = (yv[e] - mv[e]) * rv[e] * gv[e] + bv[e];
    h = fmaxf(h, 0.f);
    if constexpr (LAST) h += cres[i + e];
    o[e] = f2bf(h);
  }
  *(u16x4*)(out + i) = o;
}

// w1t[h][n*256+d] = w1_w[n][h][d]; w2t[n][d][h] = bf16(w2_w[n][h][d]);
// bias12 = w1_b + w2_b
__global__ __launch_bounds__(256)
void prepack_k(const float* __restrict__ w1w, const float* __restrict__ w1b,
               const float* __restrict__ w2w, const float* __restrict__ w2b,
               float* __restrict__ w1t, float* __restrict__ bias12,
               unsigned short* __restrict__ w2t)
{
  const int tid = blockIdx.x * 256 + threadIdx.x;
  if (tid < 524288) {
    const int nn = tid >> 16, rem = tid & 65535, h = rem >> 8, d = rem & 255;
    w1t[h * 2048 + nn * 256 + d] = w1w[tid];
    w2t[((long)(nn * 256 + d)) * 256 + h] = f2bf(w2w[tid]);
  }
  if (tid < 2048) bias12[tid] = w1b[tid] + w2b[tid];
}

// ---------------------------------------------------------------------------
extern "C" void kernel_launch(void* const* d_in, const int* in_sizes, int n_in,
                              void* d_out, int out_size, void* d_ws, size_t ws_size,
                              hipStream_t stream)
{
  const int*   seq    = (const int*)  d_in[0];
  const float* topic  = (const float*)d_in[1];
  const float* dr_w   = (const float*)d_in[2];
  const float* dr_b   = (const float*)d_in[3];
  const float* w1_w   = (const float*)d_in[4];
  const float* w1_b   = (const float*)d_in[5];
  const float* w2_w   = (const float*)d_in[6];
  const float* w2_b   = (const float*)d_in[7];
  const float* v_w    = (const float*)d_in[8];
  const float* lin0_w = (const float*)d_in[9];
  const float* lin0_b = (const float*)d_in[10];
  const float* l1_w   = (const float*)d_in[11];
  const float* l1_b   = (const float*)d_in[12];
  const float* g1     = (const float*)d_in[13];
  const float* be1    = (const float*)d_in[14];
  const float* l2_w   = (const float*)d_in[15];
  const float* l2_b   = (const float*)d_in[16];
  const float* g2     = (const float*)d_in[17];
  const float* be2    = (const float*)d_in[18];
  const float* l3_w   = (const float*)d_in[19];
  const float* l3_b   = (const float*)d_in[20];
  const float* g3     = (const float*)d_in[21];
  const float* be3    = (const float*)d_in[22];
  const float* out_w  = (const float*)d_in[23];
  float* outp = (float*)d_out;

  char* ws = (char*)d_ws;
  size_t off = 0;
  auto alloc = [&](size_t bytes) -> void* {
    void* p = ws + off;
    off += (bytes + 255) & ~(size_t)255;
    return p;
  };
  unsigned short* fea    = (unsigned short*)alloc(25600ull * 256 * 2);
  unsigned short* w2t    = (unsigned short*)alloc(8ull * 256 * 256 * 2);
  float* w1t             = (float*)alloc(256ull * 2048 * 4);
  float* bias12          = (float*)alloc(2048ull * 4);
  float* q1buf           = (float*)alloc(512ull * 2048 * 4);
  float* alphab          = (float*)alloc(512ull * 8 * 50 * 4);
  unsigned short* cfin   = (unsigned short*)alloc(512ull * 4096 * 2);
  float* c_f32           = (float*)alloc(512ull * 256 * 4);
  unsigned short* c_bf   = (unsigned short*)alloc(512ull * 256 * 2);
  float* ybuf            = (float*)alloc(512ull * 256 * 4);
  float* meanb           = (float*)alloc(256ull * 4);
  float* rstdb           = (float*)alloc(256ull * 4);
  unsigned short* h_bf   = (unsigned short*)alloc(512ull * 256 * 2);
  unsigned short* hc_bf  = (unsigned short*)alloc(512ull * 256 * 2);

  // 0) weight prepack
  hipLaunchKernelGGL(prepack_k, dim3(2048), dim3(256), 0, stream,
                     w1_w, w1_b, w2_w, w2_b, w1t, bias12, w2t);

  // 1) fea = relu(topic[seq] @ dr_w + dr_b)   -> bf16 [25600][256]
  hipLaunchKernelGGL((gemm_k<128,128,false,true,true,2>), dim3(200, 2), dim3(256), 0, stream,
                     (const void*)topic, 512, 1, 0, seq, dr_w, 256, dr_b,
                     (float*)nullptr, fea, 256, 25600, 256, 512);

  // 2) q1 = ht @ w1t + (w1_b + w2_b)  -> f32 [512][2048]   (ht = fea row m*50+49)
  hipLaunchKernelGGL((gemm_k<64,64,true,false,false,1>), dim3(8, 32), dim3(256), 0, stream,
                     (const void*)fea, 256, 50, 49, (const int*)nullptr, w1t, 2048, bias12,
                     q1buf, (unsigned short*)nullptr, 2048, 512, 2048, 256);

  // 3) fused q2 + sigmoid + dot(v_w) -> alpha [512][8][50]
  hipLaunchKernelGGL(alpha_k, dim3(400, 8), dim3(256), 0, stream,
                     fea, w2t, q1buf, v_w, alphab);

  // 4) c_final assembly -> bf16 [512][4096]
  hipLaunchKernelGGL(cfinal_k, dim3(512), dim3(256), 0, stream, fea, alphab, seq, cfin);

  // 5) c = relu(c_final @ lin0_w + lin0_b) -> f32 + bf16
  hipLaunchKernelGGL((gemm_k<64,64,true,false,true,3>), dim3(8, 4), dim3(256), 0, stream,
                     (const void*)cfin, 4096, 1, 0, (const int*)nullptr, lin0_w, 256, lin0_b,
                     c_f32, c_bf, 256, 512, 256, 4096);

  // 6) layer 1
  hipLaunchKernelGGL((gemm_k<64,64,true,false,false,1>), dim3(8, 4), dim3(256), 0, stream,
                     (const void*)c_bf, 256, 1, 0, (const int*)nullptr, l1_w, 256, l1_b,
                     ybuf, (unsigned short*)nullptr, 256, 512, 256, 256);
  hipLaunchKernelGGL(bnstat_k, dim3(32), dim3(256), 0, stream, ybuf, meanb, rstdb);
  hipLaunchKernelGGL((bnapply_k<false>), dim3(128), dim3(256), 0, stream,
                     ybuf, meanb, rstdb, g1, be1, (const float*)nullptr, h_bf);

  // 7) layer 2
  hipLaunchKernelGGL((gemm_k<64,64,true,false,false,1>), dim3(8, 4), dim3(256), 0, stream,
                     (const void*)h_bf, 256, 1, 0, (const int*)nullptr, l2_w, 256, l2_b,
                     ybuf, (unsigned short*)nullptr, 256, 512, 256, 256);
  hipLaunchKernelGGL(bnstat_k, dim3(32), dim3(256), 0, stream, ybuf, meanb, rstdb);
  hipLaunchKernelGGL((bnapply_k<false>), dim3(128), dim3(256), 0, stream,
                     ybuf, meanb, rstdb, g2, be2, (const float*)nullptr, h_bf);

  // 8) layer 3 + residual add c
  hipLaunchKernelGGL((gemm_k<64,64,true,false,false,1>), dim3(8, 4), dim3(256), 0, stream,
                     (const void*)h_bf, 256, 1, 0, (const int*)nullptr, l3_w, 256, l3_b,
                     ybuf, (unsigned short*)nullptr, 256, 512, 256, 256);
  hipLaunchKernelGGL(bnstat_k, dim3(32), dim3(256), 0, stream, ybuf, meanb, rstdb);
  hipLaunchKernelGGL((bnapply_k<true>), dim3(128), dim3(256), 0, stream,
                     ybuf, meanb, rstdb, g3, be3, c_f32, hc_bf);

  // 9) out = (h + c) @ out_w  -> f32 [512][49999]
  hipLaunchKernelGGL((gemm_k<128,128,true,false,false,1>), dim3(4, 391), dim3(256), 0, stream,
                     (const void*)hc_bf, 256, 1, 0, (const int*)nullptr, out_w, 49999,
                     (const float*)nullptr, outp, (unsigned short*)nullptr, 49999, 512, 49999, 256);

  (void)in_sizes; (void)n_in; (void)out_size; (void)ws_size;
}

// Round 2
// 597.069 us; speedup vs baseline: 1.2613x; 1.2613x over previous
//
#include <hip/hip_runtime.h>

typedef __attribute__((ext_vector_type(4))) float f32x4;
typedef __attribute__((ext_vector_type(4))) unsigned int u32x4;
typedef __attribute__((ext_vector_type(8))) short short8;
typedef __attribute__((ext_vector_type(4))) unsigned short u16x4;

#define DEV static __device__ __forceinline__

DEV unsigned short f2bf(float f) {
  union { float f; unsigned u; } v; v.f = f;
  unsigned r = v.u + 0x7fffu + ((v.u >> 16) & 1u);
  return (unsigned short)(r >> 16);
}
DEV float bf2f(unsigned short s) {
  union { unsigned u; float f; } v; v.u = ((unsigned)s) << 16;
  return v.f;
}

constexpr int KS = 32;   // K-step
constexpr int LR = 40;   // LDS row: 32 + 8 pad -> 80B rows, 16B aligned, ~2-way banks

// ---------------------------------------------------------------------------
// Generic bf16 MFMA GEMM: C[M,N] = act( bf16(A) * bf16(B) + bias )
// A: f32 (with optional row gather) or bf16, row index = gidx[m] or m*rmul+radd
// B: f32 [K][N] row-major, converted+transposed into LDS
// OUTM: bit0 -> f32 out, bit1 -> bf16 out
// SPLITK: K param is the per-split chunk; blockIdx.z selects chunk; partials
//         written at Cf + z*M*ldc (use bias=nullptr, RELU=false, OUTM=1).
// ---------------------------------------------------------------------------
template<int BM, int BN, bool ABF16, bool GATHER, bool RELU, int OUTM, bool SPLITK = false>
__global__ __launch_bounds__(256)
void gemm_k(const void* __restrict__ Av, int lda, int rmul, int radd,
            const int* __restrict__ gidx,
            const float* __restrict__ Bp, int ldb,
            const float* __restrict__ bias,
            float* __restrict__ Cf, unsigned short* __restrict__ Cb, int ldc,
            int M, int N, int K)
{
  constexpr int WM = BM / 2, WN = BN / 2, FM = WM / 16, FN = WN / 16;
  __shared__ unsigned short As[2][BM][LR];
  __shared__ unsigned short Bs[2][BN][LR];
  const int tid = threadIdx.x;
  const int lane = tid & 63;
  const int wid = tid >> 6;
  const int wy = wid >> 1, wx = wid & 1;
  const long m0 = (long)blockIdx.x * BM;
  const int n0 = blockIdx.y * BN;
  const int kbeg = SPLITK ? blockIdx.z * K : 0;
  if constexpr (SPLITK) Cf += (long)blockIdx.z * M * ldc;

  f32x4 acc[FM][FN];
#pragma unroll
  for (int i = 0; i < FM; ++i)
#pragma unroll
    for (int j = 0; j < FN; ++j) acc[i][j] = (f32x4)0.f;

  const int nsteps = K / KS;

  auto stageA = [&](int ks, int buf) {
    const int k0 = kbeg + ks * KS;
    if constexpr (!ABF16) {
      const float* A = (const float*)Av;
#pragma unroll
      for (int p = 0; p < BM / 32; ++p) {
        const int r = p * 32 + (tid >> 3);
        const int kq = tid & 7;
        long ar = GATHER ? (long)gidx[m0 + r] : ((m0 + r) * (long)rmul + radd);
        f32x4 v = *(const f32x4*)(A + ar * lda + k0 + kq * 4);
        u16x4 o;
        o[0] = f2bf(v[0]); o[1] = f2bf(v[1]); o[2] = f2bf(v[2]); o[3] = f2bf(v[3]);
        *(u16x4*)(&As[buf][r][kq * 4]) = o;
      }
    } else {
      const unsigned short* A = (const unsigned short*)Av;
#pragma unroll
      for (int p = 0; p < BM / 64; ++p) {
        const int r = p * 64 + (tid >> 2);
        const int cq = tid & 3;
        long ar = (m0 + r) * (long)rmul + radd;
        u32x4 v = *(const u32x4*)(A + ar * lda + k0 + cq * 8);
        *(u32x4*)(&As[buf][r][cq * 8]) = v;
      }
    }
  };

  auto stageB = [&](int ks, int buf) {
    const int k0 = kbeg + ks * KS;
    constexpr int NC = BN / 4;
#pragma unroll
    for (int p = 0; p < (KS * NC) / 256; ++p) {
      const int n4 = tid % NC;
      const int k = p * (256 / NC) + tid / NC;
      const int c0 = n0 + n4 * 4;
      f32x4 v;
      if (c0 + 3 < N) {
        v = *(const f32x4*)(Bp + (long)(k0 + k) * ldb + c0);
      } else {
#pragma unroll
        for (int e = 0; e < 4; ++e)
          v[e] = (c0 + e < N) ? Bp[(long)(k0 + k) * ldb + c0 + e] : 0.f;
      }
      Bs[buf][n4 * 4 + 0][k] = f2bf(v[0]);
      Bs[buf][n4 * 4 + 1][k] = f2bf(v[1]);
      Bs[buf][n4 * 4 + 2][k] = f2bf(v[2]);
      Bs[buf][n4 * 4 + 3][k] = f2bf(v[3]);
    }
  };

  stageA(0, 0); stageB(0, 0);

  for (int ks = 0; ks < nsteps; ++ks) {
    __syncthreads();
    if (ks + 1 < nsteps) { stageA(ks + 1, (ks + 1) & 1); stageB(ks + 1, (ks + 1) & 1); }
    const int buf = ks & 1;
    short8 ar[FM], br[FN];
#pragma unroll
    for (int fm = 0; fm < FM; ++fm)
      ar[fm] = *(const short8*)(&As[buf][wy * WM + fm * 16 + (lane & 15)][(lane >> 4) * 8]);
#pragma unroll
    for (int fn = 0; fn < FN; ++fn)
      br[fn] = *(const short8*)(&Bs[buf][wx * WN + fn * 16 + (lane & 15)][(lane >> 4) * 8]);
#pragma unroll
    for (int fm = 0; fm < FM; ++fm)
#pragma unroll
      for (int fn = 0; fn < FN; ++fn)
        acc[fm][fn] = __builtin_amdgcn_mfma_f32_16x16x32_bf16(ar[fm], br[fn], acc[fm][fn], 0, 0, 0);
  }

#pragma unroll
  for (int fm = 0; fm < FM; ++fm) {
    const long row0 = m0 + wy * WM + fm * 16 + ((lane >> 4) << 2);
#pragma unroll
    for (int fn = 0; fn < FN; ++fn) {
      const int col = n0 + wx * WN + fn * 16 + (lane & 15);
      if (col >= N) continue;
      const float bv = bias ? bias[col] : 0.f;
#pragma unroll
      for (int j = 0; j < 4; ++j) {
        float v = acc[fm][fn][j] + bv;
        if constexpr (RELU) v = fmaxf(v, 0.f);
        const long r = row0 + j;
        if constexpr (OUTM & 1) Cf[r * ldc + col] = v;
        if constexpr (OUTM & 2) Cb[r * ldc + col] = f2bf(v);
      }
    }
  }
}

// ---------------------------------------------------------------------------
// Fused alpha kernel: q2 tile via MFMA, then alpha = sum_d sigmoid(q2+q1)*v_w
// ---------------------------------------------------------------------------
__global__ __launch_bounds__(256)
void alpha_k(const unsigned short* __restrict__ fea,   // [25600][256] bf16
             const unsigned short* __restrict__ w2t,   // [8][256(d)][256(h)] bf16
             const float* __restrict__ q1buf,          // [512][2048]
             const float* __restrict__ vw,             // [8][256]
             float* __restrict__ alpha)                // [512][8][50]
{
  __shared__ unsigned short As[2][64][LR];
  __shared__ unsigned short Bs[2][256][LR];
  __shared__ float vws[256];
  __shared__ float red[4][64];
  const int tid = threadIdx.x;
  const int lane = tid & 63;
  const int w = tid >> 6;
  const int m0 = blockIdx.x * 64;
  const int n = blockIdx.y;

  vws[tid] = vw[n * 256 + tid];

  f32x4 acc[4][4];
#pragma unroll
  for (int i = 0; i < 4; ++i)
#pragma unroll
    for (int j = 0; j < 4; ++j) acc[i][j] = (f32x4)0.f;

  auto stageA = [&](int ks, int buf) {
    const int k0 = ks * KS;
    const int r = tid >> 2, cq = tid & 3;
    u32x4 v = *(const u32x4*)(fea + (long)(m0 + r) * 256 + k0 + cq * 8);
    *(u32x4*)(&As[buf][r][cq * 8]) = v;
  };
  auto stageB = [&](int ks, int buf) {
    const int k0 = ks * KS;
#pragma unroll
    for (int p = 0; p < 4; ++p) {
      const int r = p * 64 + (tid >> 2), cq = tid & 3;
      u32x4 v = *(const u32x4*)(w2t + ((long)(n * 256 + r)) * 256 + k0 + cq * 8);
      *(u32x4*)(&Bs[buf][r][cq * 8]) = v;
    }
  };

  stageA(0, 0); stageB(0, 0);
  for (int ks = 0; ks < 8; ++ks) {
    __syncthreads();
    if (ks < 7) { stageA(ks + 1, (ks + 1) & 1); stageB(ks + 1, (ks + 1) & 1); }
    const int buf = ks & 1;
    short8 ar[4], br[4];
#pragma unroll
    for (int fm = 0; fm < 4; ++fm)
      ar[fm] = *(const short8*)(&As[buf][fm * 16 + (lane & 15)][(lane >> 4) * 8]);
#pragma unroll
    for (int fn = 0; fn < 4; ++fn)
      br[fn] = *(const short8*)(&Bs[buf][w * 64 + fn * 16 + (lane & 15)][(lane >> 4) * 8]);
#pragma unroll
    for (int fm = 0; fm < 4; ++fm)
#pragma unroll
      for (int fn = 0; fn < 4; ++fn)
        acc[fm][fn] = __builtin_amdgcn_mfma_f32_16x16x32_bf16(ar[fm], br[fn], acc[fm][fn], 0, 0, 0);
  }

  const int g = lane >> 4, c = lane & 15;
  float part[4][4];
#pragma unroll
  for (int fm = 0; fm < 4; ++fm) {
#pragma unroll
    for (int j = 0; j < 4; ++j) {
      const int m = m0 + fm * 16 + g * 4 + j;
      const int b = m / 50;
      float p = 0.f;
#pragma unroll
      for (int fn = 0; fn < 4; ++fn) {
        const int col = w * 64 + fn * 16 + c;
        const float q = acc[fm][fn][j] + q1buf[(long)b * 2048 + n * 256 + col];
        const float s = 1.f / (1.f + __expf(-q));
        p += s * vws[col];
      }
      part[fm][j] = p;
    }
  }
#pragma unroll
  for (int fm = 0; fm < 4; ++fm)
#pragma unroll
    for (int j = 0; j < 4; ++j)
#pragma unroll
      for (int off = 1; off < 16; off <<= 1)
        part[fm][j] += __shfl_xor(part[fm][j], off);
  if (c == 0) {
#pragma unroll
    for (int fm = 0; fm < 4; ++fm)
#pragma unroll
      for (int j = 0; j < 4; ++j)
        red[w][fm * 16 + g * 4 + j] = part[fm][j];
  }
  __syncthreads();
  if (tid < 64) {
    const float s = red[0][tid] + red[1][tid] + red[2][tid] + red[3][tid];
    const int m = m0 + tid;
    const int b = m / 50, l = m - b * 50;
    alpha[((long)b * 8 + n) * 50 + l] = s;
  }
}

// ---------------------------------------------------------------------------
// c_final assembly, compact layout [b][2304]: n*256+h = a_n, 2048+h = ht
// ---------------------------------------------------------------------------
__global__ __launch_bounds__(256)
void cfinal_k(const unsigned short* __restrict__ fea,
              const float* __restrict__ alpha,
              const int* __restrict__ seq,
              unsigned short* __restrict__ cfin)
{
  __shared__ unsigned short feas[50][256];
  __shared__ float al[8][50];
  const int b = blockIdx.x, t = threadIdx.x;
#pragma unroll 1
  for (int l = 0; l < 50; ++l)
    feas[l][t] = fea[((long)b * 50 + l) * 256 + t];
  for (int i = t; i < 400; i += 256) {
    const int nn = i / 50, l = i - nn * 50;
    const float mk = (seq[b * 50 + l] > 0) ? 1.f : 0.f;
    al[nn][l] = alpha[((long)b * 8 + nn) * 50 + l] * mk;
  }
  __syncthreads();
#pragma unroll 1
  for (int nn = 0; nn < 8; ++nn) {
    float acc = 0.f;
#pragma unroll
    for (int l = 0; l < 50; ++l) acc += al[nn][l] * bf2f(feas[l][t]);
    cfin[(long)b * 2304 + nn * 256 + t] = f2bf(acc);
  }
  cfin[(long)b * 2304 + 2048 + t] = feas[49][t];
}

// ---------------------------------------------------------------------------
// lin0 split-K reduce: sum 8 partials + bias + relu -> f32 + bf16
// ---------------------------------------------------------------------------
__global__ __launch_bounds__(256)
void lin0red_k(const float* __restrict__ part, const float* __restrict__ bias,
               float* __restrict__ cf, unsigned short* __restrict__ cb)
{
  const int e = blockIdx.x * 256 + threadIdx.x;
  float s = bias[e & 255];
#pragma unroll
  for (int z = 0; z < 8; ++z) s += part[z * 131072 + e];
  s = fmaxf(s, 0.f);
  cf[e] = s;
  cb[e] = f2bf(s);
}

// ---------------------------------------------------------------------------
// Fused BatchNorm (stats + apply + relu [+ residual]) over 512 rows, 256 cols
// ---------------------------------------------------------------------------
template<bool LAST>
__global__ __launch_bounds__(256)
void bn_k(const float* __restrict__ y, const float* __restrict__ g,
          const float* __restrict__ be, const float* __restrict__ cres,
          unsigned short* __restrict__ out)
{
  const int t = threadIdx.x;
  const int col = blockIdx.x * 8 + (t & 7);
  const int rg = t >> 3;
  float v[16];
  float s = 0.f, q = 0.f;
#pragma unroll
  for (int i = 0; i < 16; ++i) {
    v[i] = y[(rg + i * 32) * 256 + col];
    s += v[i]; q += v[i] * v[i];
  }
  for (int off = 8; off < 64; off <<= 1) { s += __shfl_xor(s, off); q += __shfl_xor(q, off); }
  __shared__ float ps[4][8], pq[4][8], mm[8], rr[8];
  if ((t & 63) < 8) { ps[t >> 6][t & 7] = s; pq[t >> 6][t & 7] = q; }
  __syncthreads();
  if (t < 8) {
    const float S = ps[0][t] + ps[1][t] + ps[2][t] + ps[3][t];
    const float Q = pq[0][t] + pq[1][t] + pq[2][t] + pq[3][t];
    const float m = S * (1.f / 512.f);
    const float var = Q * (1.f / 512.f) - m * m;
    mm[t] = m;
    rr[t] = rsqrtf(var + 1e-5f);
  }
  __syncthreads();
  const float m = mm[t & 7], r = rr[t & 7], gg = g[col], bb = be[col];
#pragma unroll
  for (int i = 0; i < 16; ++i) {
    float h = (v[i] - m) * r * gg + bb;
    h = fmaxf(h, 0.f);
    if constexpr (LAST) h += cres[(rg + i * 32) * 256 + col];
    out[(rg + i * 32) * 256 + col] = f2bf(h);
  }
}

// ---------------------------------------------------------------------------
// prepack: w1t[h][n*256+d]=w1_w[n][h][d]; w2t[n][d][h]=bf16(w2_w[n][h][d]);
// bias12 = w1_b + w2_b
// ---------------------------------------------------------------------------
__global__ __launch_bounds__(256)
void prepack_k(const float* __restrict__ w1w, const float* __restrict__ w1b,
               const float* __restrict__ w2w, const float* __restrict__ w2b,
               float* __restrict__ w1t, float* __restrict__ bias12,
               unsigned short* __restrict__ w2t)
{
  const int tid = blockIdx.x * 256 + threadIdx.x;
  if (tid < 524288) {
    const int nn = tid >> 16, rem = tid & 65535, h = rem >> 8, d = rem & 255;
    w1t[h * 2048 + nn * 256 + d] = w1w[tid];
    w2t[((long)(nn * 256 + d)) * 256 + h] = f2bf(w2w[tid]);
  }
  if (tid < 2048) bias12[tid] = w1b[tid] + w2b[tid];
}

// wcat [2304][256]: rows n*256+h = lin0_w[n*512+h]; rows 2048+h = sum_n lin0_w[n*512+256+h]
__global__ __launch_bounds__(256)
void prepack2_k(const float* __restrict__ lin0w, float* __restrict__ wcat)
{
  const int e = blockIdx.x * 256 + threadIdx.x;   // 0..589823
  const int h2 = e >> 8, d = e & 255;
  float v;
  if (h2 < 2048) {
    const int n = h2 >> 8, h = h2 & 255;
    v = lin0w[((n * 512 + h) << 8) + d];
  } else {
    const int h = h2 - 2048;
    v = 0.f;
#pragma unroll
    for (int n = 0; n < 8; ++n) v += lin0w[((n * 512 + 256 + h) << 8) + d];
  }
  wcat[e] = v;
}

// ---------------------------------------------------------------------------
extern "C" void kernel_launch(void* const* d_in, const int* in_sizes, int n_in,
                              void* d_out, int out_size, void* d_ws, size_t ws_size,
                              hipStream_t stream)
{
  const int*   seq    = (const int*)  d_in[0];
  const float* topic  = (const float*)d_in[1];
  const float* dr_w   = (const float*)d_in[2];
  const float* dr_b   = (const float*)d_in[3];
  const float* w1_w   = (const float*)d_in[4];
  const float* w1_b   = (const float*)d_in[5];
  const float* w2_w   = (const float*)d_in[6];
  const float* w2_b   = (const float*)d_in[7];
  const float* v_w    = (const float*)d_in[8];
  const float* lin0_w = (const float*)d_in[9];
  const float* lin0_b = (const float*)d_in[10];
  const float* l1_w   = (const float*)d_in[11];
  const float* l1_b   = (const float*)d_in[12];
  const float* g1     = (const float*)d_in[13];
  const float* be1    = (const float*)d_in[14];
  const float* l2_w   = (const float*)d_in[15];
  const float* l2_b   = (const float*)d_in[16];
  const float* g2     = (const float*)d_in[17];
  const float* be2    = (const float*)d_in[18];
  const float* l3_w   = (const float*)d_in[19];
  const float* l3_b   = (const float*)d_in[20];
  const float* g3     = (const float*)d_in[21];
  const float* be3    = (const float*)d_in[22];
  const float* out_w  = (const float*)d_in[23];
  float* outp = (float*)d_out;

  char* ws = (char*)d_ws;
  size_t off = 0;
  auto alloc = [&](size_t bytes) -> void* {
    void* p = ws + off;
    off += (bytes + 255) & ~(size_t)255;
    return p;
  };
  unsigned short* fea    = (unsigned short*)alloc(25600ull * 256 * 2);
  unsigned short* w2t    = (unsigned short*)alloc(8ull * 256 * 256 * 2);
  float* w1t             = (float*)alloc(256ull * 2048 * 4);
  float* bias12          = (float*)alloc(2048ull * 4);
  float* q1buf           = (float*)alloc(512ull * 2048 * 4);
  float* alphab          = (float*)alloc(512ull * 8 * 50 * 4);
  unsigned short* cfin   = (unsigned short*)alloc(512ull * 2304 * 2);
  float* wcat            = (float*)alloc(2304ull * 256 * 4);
  float* part            = (float*)alloc(8ull * 512 * 256 * 4);   // also reused as ybuf
  float* c_f32           = (float*)alloc(512ull * 256 * 4);
  unsigned short* c_bf   = (unsigned short*)alloc(512ull * 256 * 2);
  unsigned short* h_bf   = (unsigned short*)alloc(512ull * 256 * 2);
  unsigned short* hc_bf  = (unsigned short*)alloc(512ull * 256 * 2);
  float* ybuf = part;   // l1-l3 GEMM outputs reuse the split-K partial buffer

  // 0) weight prepack
  hipLaunchKernelGGL(prepack_k, dim3(2048), dim3(256), 0, stream,
                     w1_w, w1_b, w2_w, w2_b, w1t, bias12, w2t);
  hipLaunchKernelGGL(prepack2_k, dim3(2304), dim3(256), 0, stream, lin0_w, wcat);

  // 1) fea = relu(topic[seq] @ dr_w + dr_b)   -> bf16 [25600][256]
  hipLaunchKernelGGL((gemm_k<128,128,false,true,true,2>), dim3(200, 2), dim3(256), 0, stream,
                     (const void*)topic, 512, 1, 0, seq, dr_w, 256, dr_b,
                     (float*)nullptr, fea, 256, 25600, 256, 512);

  // 2) q1 = ht @ w1t + (w1_b + w2_b)  -> f32 [512][2048]   (ht = fea row m*50+49)
  hipLaunchKernelGGL((gemm_k<64,64,true,false,false,1>), dim3(8, 32), dim3(256), 0, stream,
                     (const void*)fea, 256, 50, 49, (const int*)nullptr, w1t, 2048, bias12,
                     q1buf, (unsigned short*)nullptr, 2048, 512, 2048, 256);

  // 3) fused q2 + sigmoid + dot(v_w) -> alpha [512][8][50]
  hipLaunchKernelGGL(alpha_k, dim3(400, 8), dim3(256), 0, stream,
                     fea, w2t, q1buf, v_w, alphab);

  // 4) c_final assembly -> bf16 [512][2304]
  hipLaunchKernelGGL(cfinal_k, dim3(512), dim3(256), 0, stream, fea, alphab, seq, cfin);

  // 5) c = relu(cfin @ wcat + lin0_b): split-K=8 partials then reduce
  hipLaunchKernelGGL((gemm_k<64,64,true,false,false,1,true>), dim3(8, 4, 8), dim3(256), 0, stream,
                     (const void*)cfin, 2304, 1, 0, (const int*)nullptr, wcat, 256,
                     (const float*)nullptr, part, (unsigned short*)nullptr, 256, 512, 256, 288);
  hipLaunchKernelGGL(lin0red_k, dim3(512), dim3(256), 0, stream, part, lin0_b, c_f32, c_bf);

  // 6) layer 1
  hipLaunchKernelGGL((gemm_k<64,64,true,false,false,1>), dim3(8, 4), dim3(256), 0, stream,
                     (const void*)c_bf, 256, 1, 0, (const int*)nullptr, l1_w, 256, l1_b,
                     ybuf, (unsigned short*)nullptr, 256, 512, 256, 256);
  hipLaunchKernelGGL((bn_k<false>), dim3(32), dim3(256), 0, stream,
                     ybuf, g1, be1, (const float*)nullptr, h_bf);

  // 7) layer 2
  hipLaunchKernelGGL((gemm_k<64,64,true,false,false,1>), dim3(8, 4), dim3(256), 0, stream,
                     (const void*)h_bf, 256, 1, 0, (const int*)nullptr, l2_w, 256, l2_b,
                     ybuf, (unsigned short*)nullptr, 256, 512, 256, 256);
  hipLaunchKernelGGL((bn_k<false>), dim3(32), dim3(256), 0, stream,
                     ybuf, g2, be2, (const float*)nullptr, h_bf);

  // 8) layer 3 + residual add c
  hipLaunchKernelGGL((gemm_k<64,64,true,false,false,1>), dim3(8, 4), dim3(256), 0, stream,
                     (const void*)h_bf, 256, 1, 0, (const int*)nullptr, l3_w, 256, l3_b,
                     ybuf, (unsigned short*)nullptr, 256, 512, 256, 256);
  hipLaunchKernelGGL((bn_k<true>), dim3(32), dim3(256), 0, stream,
                     ybuf, g3, be3, c_f32, hc_bf);

  // 9) out = (h + c) @ out_w  -> f32 [512][49999]
  hipLaunchKernelGGL((gemm_k<128,128,true,false,false,1>), dim3(4, 391), dim3(256), 0, stream,
                     (const void*)hc_bf, 256, 1, 0, (const int*)nullptr, out_w, 49999,
                     (const float*)nullptr, outp, (unsigned short*)nullptr, 49999, 512, 49999, 256);

  (void)in_sizes; (void)n_in; (void)out_size; (void)ws_size;
}

// Round 4
// 509.386 us; speedup vs baseline: 1.4785x; 1.1721x over previous
//
#include <hip/hip_runtime.h>

typedef __attribute__((ext_vector_type(4))) float f32x4;
typedef __attribute__((ext_vector_type(4))) unsigned int u32x4;
typedef __attribute__((ext_vector_type(8))) short short8;
typedef __attribute__((ext_vector_type(4))) unsigned short u16x4;

#define DEV static __device__ __forceinline__

DEV unsigned short f2bf(float f) {
  union { float f; unsigned u; } v; v.f = f;
  unsigned r = v.u + 0x7fffu + ((v.u >> 16) & 1u);
  return (unsigned short)(r >> 16);
}
DEV float bf2f(unsigned short s) {
  union { unsigned u; float f; } v; v.u = ((unsigned)s) << 16;
  return v.f;
}

constexpr int KS = 32;   // K-step
constexpr int LR = 40;   // LDS row: 32 + 8 pad -> 80B rows, 16B aligned, ~2-way banks

// ---------------------------------------------------------------------------
// Generic bf16 MFMA GEMM: C[M,N] = act( bf16(A) * bf16(B) + bias )
// A: f32 (opt. row gather) or bf16; row = gidx[m] or m*rmul+radd
// BMODE 0: B f32 [K][ldb] row-major (cvt+transpose in staging)
// BMODE 1: B bf16 packed [K/32][ldb][32] (fragment-order; pure 16B copies)
// OUTM: bit0 -> f32 out, bit1 -> bf16 out
// SPLITK: K = per-chunk; blockIdx.z selects chunk; partial at Cf + z*M*ldc
// SWZ: bijective XCD swizzle so consecutive work ids share an XCD L2
// ---------------------------------------------------------------------------
template<int BM, int BN, int TH, int WY, int WX, bool ABF16, bool GATHER,
         int BMODE, bool RELU, int OUTM, bool SPLITK, bool SWZ>
__global__ __launch_bounds__(TH)
void gemm_k(const void* __restrict__ Av, int lda, int rmul, int radd,
            const int* __restrict__ gidx,
            const void* __restrict__ Bp, int ldb,
            const float* __restrict__ bias,
            float* __restrict__ Cf, unsigned short* __restrict__ Cb, int ldc,
            int M, int N, int K)
{
  constexpr int WM = BM / WY, WN = BN / WX, FM = WM / 16, FN = WN / 16;
  __shared__ unsigned short As[2][BM][LR];
  __shared__ unsigned short Bs[2][BN][LR];
  const int tid = threadIdx.x;
  const int lane = tid & 63;
  const int wid = tid >> 6;
  const int wy = wid / WX, wx = wid % WX;
  int bx = blockIdx.x, by = blockIdx.y;
  if constexpr (SWZ) {
    const int gx = gridDim.x, total = gx * gridDim.y;
    const int bid = by * gx + bx;
    const int q = total >> 3, r = total & 7;
    const int xcd = bid & 7, idx = bid >> 3;
    const int j = (xcd < r ? xcd * (q + 1) : r * (q + 1) + (xcd - r) * q) + idx;
    bx = j % gx; by = j / gx;
  }
  const long m0 = (long)bx * BM;
  const int n0 = by * BN;
  const int kbeg = SPLITK ? blockIdx.z * K : 0;
  if constexpr (SPLITK) Cf += (long)blockIdx.z * M * ldc;

  f32x4 acc[FM][FN];
#pragma unroll
  for (int i = 0; i < FM; ++i)
#pragma unroll
    for (int j = 0; j < FN; ++j) acc[i][j] = (f32x4)0.f;

  const int nsteps = K / KS;

  auto stageA = [&](int ks, int buf) {
    const int k0 = kbeg + ks * KS;
    if constexpr (!ABF16) {
      const float* A = (const float*)Av;
#pragma unroll
      for (int p = 0; p < BM / (TH / 8); ++p) {
        const int r = p * (TH / 8) + (tid >> 3);
        const int kq = tid & 7;
        long ar = GATHER ? (long)gidx[m0 + r] : ((m0 + r) * (long)rmul + radd);
        f32x4 v = *(const f32x4*)(A + ar * lda + k0 + kq * 4);
        u16x4 o;
        o[0] = f2bf(v[0]); o[1] = f2bf(v[1]); o[2] = f2bf(v[2]); o[3] = f2bf(v[3]);
        *(u16x4*)(&As[buf][r][kq * 4]) = o;
      }
    } else {
      const unsigned short* A = (const unsigned short*)Av;
#pragma unroll
      for (int p = 0; p < BM / (TH / 4); ++p) {
        const int r = p * (TH / 4) + (tid >> 2);
        const int cq = tid & 3;
        long ar = (m0 + r) * (long)rmul + radd;
        u32x4 v = *(const u32x4*)(A + ar * lda + k0 + cq * 8);
        *(u32x4*)(&As[buf][r][cq * 8]) = v;
      }
    }
  };

  auto stageB = [&](int ks, int buf) {
    if constexpr (BMODE == 0) {
      const float* B = (const float*)Bp;
      const int k0 = kbeg + ks * KS;
      constexpr int NC = BN / 4;
#pragma unroll
      for (int p = 0; p < (KS * NC) / TH; ++p) {
        const int n4 = tid % NC;
        const int k = p * (TH / NC) + tid / NC;
        const int c0 = n0 + n4 * 4;
        f32x4 v;
        if (c0 + 3 < N) {
          v = *(const f32x4*)(B + (long)(k0 + k) * ldb + c0);
        } else {
#pragma unroll
          for (int e = 0; e < 4; ++e)
            v[e] = (c0 + e < N) ? B[(long)(k0 + k) * ldb + c0 + e] : 0.f;
        }
        Bs[buf][n4 * 4 + 0][k] = f2bf(v[0]);
        Bs[buf][n4 * 4 + 1][k] = f2bf(v[1]);
        Bs[buf][n4 * 4 + 2][k] = f2bf(v[2]);
        Bs[buf][n4 * 4 + 3][k] = f2bf(v[3]);
      }
    } else {
      const unsigned short* B = (const unsigned short*)Bp;
      const int ksg = (kbeg / KS) + ks;
#pragma unroll
      for (int p = 0; p < (BN * 4) / TH; ++p) {
        const int cc = p * (TH / 4) + (tid >> 2);
        const int q = tid & 3;
        u32x4 v = *(const u32x4*)(B + ((long)ksg * ldb + n0 + cc) * 32 + q * 8);
        *(u32x4*)(&Bs[buf][cc][q * 8]) = v;
      }
    }
  };

  stageA(0, 0); stageB(0, 0);

  for (int ks = 0; ks < nsteps; ++ks) {
    __syncthreads();
    if (ks + 1 < nsteps) { stageA(ks + 1, (ks + 1) & 1); stageB(ks + 1, (ks + 1) & 1); }
    const int buf = ks & 1;
    short8 ar[FM], br[FN];
#pragma unroll
    for (int fm = 0; fm < FM; ++fm)
      ar[fm] = *(const short8*)(&As[buf][wy * WM + fm * 16 + (lane & 15)][(lane >> 4) * 8]);
#pragma unroll
    for (int fn = 0; fn < FN; ++fn)
      br[fn] = *(const short8*)(&Bs[buf][wx * WN + fn * 16 + (lane & 15)][(lane >> 4) * 8]);
#pragma unroll
    for (int fm = 0; fm < FM; ++fm)
#pragma unroll
      for (int fn = 0; fn < FN; ++fn)
        acc[fm][fn] = __builtin_amdgcn_mfma_f32_16x16x32_bf16(ar[fm], br[fn], acc[fm][fn], 0, 0, 0);
  }

#pragma unroll
  for (int fm = 0; fm < FM; ++fm) {
    const long row0 = m0 + wy * WM + fm * 16 + ((lane >> 4) << 2);
#pragma unroll
    for (int fn = 0; fn < FN; ++fn) {
      const int col = n0 + wx * WN + fn * 16 + (lane & 15);
      if (col >= N) continue;
      const float bv = bias ? bias[col] : 0.f;
#pragma unroll
      for (int j = 0; j < 4; ++j) {
        float v = acc[fm][fn][j] + bv;
        if constexpr (RELU) v = fmaxf(v, 0.f);
        const long r = row0 + j;
        if constexpr (OUTM & 1) Cf[r * ldc + col] = v;
        if constexpr (OUTM & 2) Cb[r * ldc + col] = f2bf(v);
      }
    }
  }
}

// ---------------------------------------------------------------------------
// packB: f32 [K][Nsrc] row-major -> bf16 packed [K/32][Ndst][32], zero-pad cols
// ---------------------------------------------------------------------------
__global__ __launch_bounds__(256)
void packB_k(const float* __restrict__ src, unsigned short* __restrict__ dst,
             int Nsrc, int Ndst)
{
  const int t = blockIdx.x * 256 + threadIdx.x;
  const int ks = t / Ndst, n = t - ks * Ndst;
  unsigned short buf[32];
#pragma unroll
  for (int kk = 0; kk < 32; ++kk)
    buf[kk] = (n < Nsrc) ? f2bf(src[(long)(ks * 32 + kk) * Nsrc + n]) : (unsigned short)0;
#pragma unroll
  for (int q = 0; q < 4; ++q)
    *(u32x4*)(dst + ((long)ks * Ndst + n) * 32 + q * 8) = *(const u32x4*)(buf + q * 8);
}

// ---------------------------------------------------------------------------
// Fused alpha kernel: q2 tile via MFMA, then alpha = sum_d sigmoid(q2+q1)*v_w
// ---------------------------------------------------------------------------
__global__ __launch_bounds__(256)
void alpha_k(const unsigned short* __restrict__ fea,   // [25600][256] bf16
             const unsigned short* __restrict__ w2t,   // [8][256(d)][256(h)] bf16
             const float* __restrict__ q1buf,          // [512][2048]
             const float* __restrict__ vw,             // [8][256]
             float* __restrict__ alpha)                // [512][8][50]
{
  __shared__ unsigned short As[2][64][LR];
  __shared__ unsigned short Bs[2][256][LR];
  __shared__ float vws[256];
  __shared__ float red[4][64];
  const int tid = threadIdx.x;
  const int lane = tid & 63;
  const int w = tid >> 6;
  const int m0 = blockIdx.x * 64;
  const int n = blockIdx.y;

  vws[tid] = vw[n * 256 + tid];

  f32x4 acc[4][4];
#pragma unroll
  for (int i = 0; i < 4; ++i)
#pragma unroll
    for (int j = 0; j < 4; ++j) acc[i][j] = (f32x4)0.f;

  auto stageA = [&](int ks, int buf) {
    const int k0 = ks * KS;
    const int r = tid >> 2, cq = tid & 3;
    u32x4 v = *(const u32x4*)(fea + (long)(m0 + r) * 256 + k0 + cq * 8);
    *(u32x4*)(&As[buf][r][cq * 8]) = v;
  };
  auto stageB = [&](int ks, int buf) {
    const int k0 = ks * KS;
#pragma unroll
    for (int p = 0; p < 4; ++p) {
      const int r = p * 64 + (tid >> 2), cq = tid & 3;
      u32x4 v = *(const u32x4*)(w2t + ((long)(n * 256 + r)) * 256 + k0 + cq * 8);
      *(u32x4*)(&Bs[buf][r][cq * 8]) = v;
    }
  };

  stageA(0, 0); stageB(0, 0);
  for (int ks = 0; ks < 8; ++ks) {
    __syncthreads();
    if (ks < 7) { stageA(ks + 1, (ks + 1) & 1); stageB(ks + 1, (ks + 1) & 1); }
    const int buf = ks & 1;
    short8 ar[4], br[4];
#pragma unroll
    for (int fm = 0; fm < 4; ++fm)
      ar[fm] = *(const short8*)(&As[buf][fm * 16 + (lane & 15)][(lane >> 4) * 8]);
#pragma unroll
    for (int fn = 0; fn < 4; ++fn)
      br[fn] = *(const short8*)(&Bs[buf][w * 64 + fn * 16 + (lane & 15)][(lane >> 4) * 8]);
#pragma unroll
    for (int fm = 0; fm < 4; ++fm)
#pragma unroll
      for (int fn = 0; fn < 4; ++fn)
        acc[fm][fn] = __builtin_amdgcn_mfma_f32_16x16x32_bf16(ar[fm], br[fn], acc[fm][fn], 0, 0, 0);
  }

  const int g = lane >> 4, c = lane & 15;
  float part[4][4];
#pragma unroll
  for (int fm = 0; fm < 4; ++fm) {
#pragma unroll
    for (int j = 0; j < 4; ++j) {
      const int m = m0 + fm * 16 + g * 4 + j;
      const int b = m / 50;
      float p = 0.f;
#pragma unroll
      for (int fn = 0; fn < 4; ++fn) {
        const int col = w * 64 + fn * 16 + c;
        const float q = acc[fm][fn][j] + q1buf[(long)b * 2048 + n * 256 + col];
        const float s = 1.f / (1.f + __expf(-q));
        p += s * vws[col];
      }
      part[fm][j] = p;
    }
  }
#pragma unroll
  for (int fm = 0; fm < 4; ++fm)
#pragma unroll
    for (int j = 0; j < 4; ++j)
#pragma unroll
      for (int off = 1; off < 16; off <<= 1)
        part[fm][j] += __shfl_xor(part[fm][j], off);
  if (c == 0) {
#pragma unroll
    for (int fm = 0; fm < 4; ++fm)
#pragma unroll
      for (int j = 0; j < 4; ++j)
        red[w][fm * 16 + g * 4 + j] = part[fm][j];
  }
  __syncthreads();
  if (tid < 64) {
    const float s = red[0][tid] + red[1][tid] + red[2][tid] + red[3][tid];
    const int m = m0 + tid;
    const int b = m / 50, l = m - b * 50;
    alpha[((long)b * 8 + n) * 50 + l] = s;
  }
}

// ---------------------------------------------------------------------------
// c_final assembly, compact layout [b][2304]: n*256+h = a_n, 2048+h = ht
// ---------------------------------------------------------------------------
__global__ __launch_bounds__(256)
void cfinal_k(const unsigned short* __restrict__ fea,
              const float* __restrict__ alpha,
              const int* __restrict__ seq,
              unsigned short* __restrict__ cfin)
{
  __shared__ unsigned short feas[50][256];
  __shared__ float al[8][50];
  const int b = blockIdx.x, t = threadIdx.x;
#pragma unroll 1
  for (int l = 0; l < 50; ++l)
    feas[l][t] = fea[((long)b * 50 + l) * 256 + t];
  for (int i = t; i < 400; i += 256) {
    const int nn = i / 50, l = i - nn * 50;
    const float mk = (seq[b * 50 + l] > 0) ? 1.f : 0.f;
    al[nn][l] = alpha[((long)b * 8 + nn) * 50 + l] * mk;
  }
  __syncthreads();
#pragma unroll 1
  for (int nn = 0; nn < 8; ++nn) {
    float acc = 0.f;
#pragma unroll
    for (int l = 0; l < 50; ++l) acc += al[nn][l] * bf2f(feas[l][t]);
    cfin[(long)b * 2304 + nn * 256 + t] = f2bf(acc);
  }
  cfin[(long)b * 2304 + 2048 + t] = feas[49][t];
}

// ---------------------------------------------------------------------------
// lin0 split-K reduce: sum 8 partials + bias + relu -> f32 + bf16
// ---------------------------------------------------------------------------
__global__ __launch_bounds__(256)
void lin0red_k(const float* __restrict__ part, const float* __restrict__ bias,
               float* __restrict__ cf, unsigned short* __restrict__ cb)
{
  const int e = blockIdx.x * 256 + threadIdx.x;
  float s = bias[e & 255];
#pragma unroll
  for (int z = 0; z < 8; ++z) s += part[z * 131072 + e];
  s = fmaxf(s, 0.f);
  cf[e] = s;
  cb[e] = f2bf(s);
}

// ---------------------------------------------------------------------------
// Fused BatchNorm: sums 4 split-K partials, stats + apply + relu [+ residual]
// (biases omitted: BN is shift-invariant, so l?_b cancel exactly)
// ---------------------------------------------------------------------------
template<bool LAST>
__global__ __launch_bounds__(256)
void bn_k(const float* __restrict__ y, const float* __restrict__ g,
          const float* __restrict__ be, const float* __restrict__ cres,
          unsigned short* __restrict__ out)
{
  const int t = threadIdx.x;
  const int col = blockIdx.x * 8 + (t & 7);
  const int rg = t >> 3;
  float v[16];
  float s = 0.f, q = 0.f;
#pragma unroll
  for (int i = 0; i < 16; ++i) {
    const int off = (rg + i * 32) * 256 + col;
    float x = y[off] + y[131072 + off] + y[262144 + off] + y[393216 + off];
    v[i] = x;
    s += x; q += x * x;
  }
  for (int off = 8; off < 64; off <<= 1) { s += __shfl_xor(s, off); q += __shfl_xor(q, off); }
  __shared__ float ps[4][8], pq[4][8], mm[8], rr[8];
  if ((t & 63) < 8) { ps[t >> 6][t & 7] = s; pq[t >> 6][t & 7] = q; }
  __syncthreads();
  if (t < 8) {
    const float S = ps[0][t] + ps[1][t] + ps[2][t] + ps[3][t];
    const float Q = pq[0][t] + pq[1][t] + pq[2][t] + pq[3][t];
    const float m = S * (1.f / 512.f);
    const float var = Q * (1.f / 512.f) - m * m;
    mm[t] = m;
    rr[t] = rsqrtf(var + 1e-5f);
  }
  __syncthreads();
  const float m = mm[t & 7], r = rr[t & 7], gg = g[col], bb = be[col];
#pragma unroll
  for (int i = 0; i < 16; ++i) {
    float h = (v[i] - m) * r * gg + bb;
    h = fmaxf(h, 0.f);
    if constexpr (LAST) h += cres[(rg + i * 32) * 256 + col];
    out[(rg + i * 32) * 256 + col] = f2bf(h);
  }
}

// ---------------------------------------------------------------------------
// prepack: w1t[h][n*256+d]=w1_w[n][h][d]; w2t[n][d][h]=bf16(w2_w[n][h][d]);
// bias12 = w1_b + w2_b
// ---------------------------------------------------------------------------
__global__ __launch_bounds__(256)
void prepack_k(const float* __restrict__ w1w, const float* __restrict__ w1b,
               const float* __restrict__ w2w, const float* __restrict__ w2b,
               float* __restrict__ w1t, float* __restrict__ bias12,
               unsigned short* __restrict__ w2t)
{
  const int tid = blockIdx.x * 256 + threadIdx.x;
  if (tid < 524288) {
    const int nn = tid >> 16, rem = tid & 65535, h = rem >> 8, d = rem & 255;
    w1t[h * 2048 + nn * 256 + d] = w1w[tid];
    w2t[((long)(nn * 256 + d)) * 256 + h] = f2bf(w2w[tid]);
  }
  if (tid < 2048) bias12[tid] = w1b[tid] + w2b[tid];
}

// wcat [2304][256]: rows n*256+h = lin0_w[n*512+h]; rows 2048+h = sum_n lin0_w[n*512+256+h]
__global__ __launch_bounds__(256)
void prepack2_k(const float* __restrict__ lin0w, float* __restrict__ wcat)
{
  const int e = blockIdx.x * 256 + threadIdx.x;   // 0..589823
  const int h2 = e >> 8, d = e & 255;
  float v;
  if (h2 < 2048) {
    const int n = h2 >> 8, h = h2 & 255;
    v = lin0w[((n * 512 + h) << 8) + d];
  } else {
    const int h = h2 - 2048;
    v = 0.f;
#pragma unroll
    for (int n = 0; n < 8; ++n) v += lin0w[((n * 512 + 256 + h) << 8) + d];
  }
  wcat[e] = v;
}

// ---------------------------------------------------------------------------
extern "C" void kernel_launch(void* const* d_in, const int* in_sizes, int n_in,
                              void* d_out, int out_size, void* d_ws, size_t ws_size,
                              hipStream_t stream)
{
  const int*   seq    = (const int*)  d_in[0];
  const float* topic  = (const float*)d_in[1];
  const float* dr_w   = (const float*)d_in[2];
  const float* dr_b   = (const float*)d_in[3];
  const float* w1_w   = (const float*)d_in[4];
  const float* w1_b   = (const float*)d_in[5];
  const float* w2_w   = (const float*)d_in[6];
  const float* w2_b   = (const float*)d_in[7];
  const float* v_w    = (const float*)d_in[8];
  const float* lin0_w = (const float*)d_in[9];
  const float* lin0_b = (const float*)d_in[10];
  const float* l1_w   = (const float*)d_in[11];
  const float* g1     = (const float*)d_in[13];
  const float* be1    = (const float*)d_in[14];
  const float* l2_w   = (const float*)d_in[15];
  const float* g2     = (const float*)d_in[17];
  const float* be2    = (const float*)d_in[18];
  const float* l3_w   = (const float*)d_in[19];
  const float* g3     = (const float*)d_in[21];
  const float* be3    = (const float*)d_in[22];
  const float* out_w  = (const float*)d_in[23];
  float* outp = (float*)d_out;

  char* ws = (char*)d_ws;
  size_t off = 0;
  auto alloc = [&](size_t bytes) -> void* {
    void* p = ws + off;
    off += (bytes + 255) & ~(size_t)255;
    return p;
  };
  unsigned short* fea    = (unsigned short*)alloc(25600ull * 256 * 2);
  unsigned short* w2t    = (unsigned short*)alloc(8ull * 256 * 256 * 2);
  float* w1t             = (float*)alloc(256ull * 2048 * 4);
  float* bias12          = (float*)alloc(2048ull * 4);
  float* q1buf           = (float*)alloc(512ull * 2048 * 4);
  float* alphab          = (float*)alloc(512ull * 8 * 50 * 4);
  unsigned short* cfin   = (unsigned short*)alloc(512ull * 2304 * 2);
  float* wcat            = (float*)alloc(2304ull * 256 * 4);
  float* part            = (float*)alloc(8ull * 512 * 256 * 4);
  float* c_f32           = (float*)alloc(512ull * 256 * 4);
  unsigned short* c_bf   = (unsigned short*)alloc(512ull * 256 * 2);
  unsigned short* h_bf   = (unsigned short*)alloc(512ull * 256 * 2);
  unsigned short* hc_bf  = (unsigned short*)alloc(512ull * 256 * 2);
  unsigned short* drwp   = (unsigned short*)alloc(16ull * 256 * 32 * 2);      // dr_w packed
  unsigned short* wpad   = (unsigned short*)alloc(8ull * 50048 * 32 * 2);     // out_w packed

  // 0) weight prepack
  hipLaunchKernelGGL(prepack_k, dim3(2048), dim3(256), 0, stream,
                     w1_w, w1_b, w2_w, w2_b, w1t, bias12, w2t);
  hipLaunchKernelGGL(prepack2_k, dim3(2304), dim3(256), 0, stream, lin0_w, wcat);
  hipLaunchKernelGGL(packB_k, dim3(16), dim3(256), 0, stream, dr_w, drwp, 256, 256);
  hipLaunchKernelGGL(packB_k, dim3(1564), dim3(256), 0, stream, out_w, wpad, 49999, 50048);

  // 1) fea = relu(topic[seq] @ dr_w + dr_b) -> bf16 [25600][256]; BN=256, no dup A reads
  hipLaunchKernelGGL((gemm_k<64,256,256,1,4, false,true, 1, true, 2, false,false>),
                     dim3(400, 1), dim3(256), 0, stream,
                     (const void*)topic, 512, 1, 0, seq, (const void*)drwp, 256, dr_b,
                     (float*)nullptr, fea, 256, 25600, 256, 512);

  // 2) q1 = ht @ w1t + (w1_b + w2_b)  -> f32 [512][2048]
  hipLaunchKernelGGL((gemm_k<64,64,256,2,2, true,false, 0, false, 1, false,false>),
                     dim3(8, 32), dim3(256), 0, stream,
                     (const void*)fea, 256, 50, 49, (const int*)nullptr,
                     (const void*)w1t, 2048, bias12,
                     q1buf, (unsigned short*)nullptr, 2048, 512, 2048, 256);

  // 3) fused q2 + sigmoid + dot(v_w) -> alpha [512][8][50]
  hipLaunchKernelGGL(alpha_k, dim3(400, 8), dim3(256), 0, stream,
                     fea, w2t, q1buf, v_w, alphab);

  // 4) c_final assembly -> bf16 [512][2304]
  hipLaunchKernelGGL(cfinal_k, dim3(512), dim3(256), 0, stream, fea, alphab, seq, cfin);

  // 5) c = relu(cfin @ wcat + lin0_b): split-K=8 partials then reduce
  hipLaunchKernelGGL((gemm_k<64,64,256,2,2, true,false, 0, false, 1, true,false>),
                     dim3(8, 4, 8), dim3(256), 0, stream,
                     (const void*)cfin, 2304, 1, 0, (const int*)nullptr,
                     (const void*)wcat, 256, (const float*)nullptr,
                     part, (unsigned short*)nullptr, 256, 512, 256, 288);
  hipLaunchKernelGGL(lin0red_k, dim3(512), dim3(256), 0, stream, part, lin0_b, c_f32, c_bf);

  // 6-8) l1..l3: split-K=4 GEMM (no bias; BN cancels it) + fused BN
  hipLaunchKernelGGL((gemm_k<64,64,256,2,2, true,false, 0, false, 1, true,false>),
                     dim3(8, 4, 4), dim3(256), 0, stream,
                     (const void*)c_bf, 256, 1, 0, (const int*)nullptr,
                     (const void*)l1_w, 256, (const float*)nullptr,
                     part, (unsigned short*)nullptr, 256, 512, 256, 64);
  hipLaunchKernelGGL((bn_k<false>), dim3(32), dim3(256), 0, stream,
                     part, g1, be1, (const float*)nullptr, h_bf);

  hipLaunchKernelGGL((gemm_k<64,64,256,2,2, true,false, 0, false, 1, true,false>),
                     dim3(8, 4, 4), dim3(256), 0, stream,
                     (const void*)h_bf, 256, 1, 0, (const int*)nullptr,
                     (const void*)l2_w, 256, (const float*)nullptr,
                     part, (unsigned short*)nullptr, 256, 512, 256, 64);
  hipLaunchKernelGGL((bn_k<false>), dim3(32), dim3(256), 0, stream,
                     part, g2, be2, (const float*)nullptr, h_bf);

  hipLaunchKernelGGL((gemm_k<64,64,256,2,2, true,false, 0, false, 1, true,false>),
                     dim3(8, 4, 4), dim3(256), 0, stream,
                     (const void*)h_bf, 256, 1, 0, (const int*)nullptr,
                     (const void*)l3_w, 256, (const float*)nullptr,
                     part, (unsigned short*)nullptr, 256, 512, 256, 64);
  hipLaunchKernelGGL((bn_k<true>), dim3(32), dim3(256), 0, stream,
                     part, g3, be3, c_f32, hc_bf);

  // 9) out = (h + c) @ out_w : packed-bf16 B + XCD swizzle (4 m-tiles share panel)
  hipLaunchKernelGGL((gemm_k<128,128,256,2,2, true,false, 1, false, 1, false,true>),
                     dim3(4, 391), dim3(256), 0, stream,
                     (const void*)hc_bf, 256, 1, 0, (const int*)nullptr,
                     (const void*)wpad, 50048, (const float*)nullptr,
                     outp, (unsigned short*)nullptr, 49999, 512, 49999, 256);

  (void)in_sizes; (void)n_in; (void)out_size; (void)ws_size;
}

// Round 5
// 479.871 us; speedup vs baseline: 1.5694x; 1.0615x over previous
//
#include <hip/hip_runtime.h>

typedef __attribute__((ext_vector_type(4))) float f32x4;
typedef __attribute__((ext_vector_type(4))) unsigned int u32x4;
typedef __attribute__((ext_vector_type(8))) short short8;
typedef __attribute__((ext_vector_type(4))) unsigned short u16x4;

#define DEV static __device__ __forceinline__

DEV unsigned short f2bf(float f) {
  union { float f; unsigned u; } v; v.f = f;
  unsigned r = v.u + 0x7fffu + ((v.u >> 16) & 1u);
  return (unsigned short)(r >> 16);
}
DEV float bf2f(unsigned short s) {
  union { unsigned u; float f; } v; v.u = ((unsigned)s) << 16;
  return v.f;
}

constexpr int KS = 32;   // K-step
constexpr int LR = 40;   // LDS row: 32 + 8 pad -> 80B rows, 16B aligned, ~2-way banks

// ---------------------------------------------------------------------------
// Generic bf16 MFMA GEMM: C[M,N] = act( bf16(A) * bf16(B) + bias )
// A: f32 (opt. row gather) or bf16; row = gidx[m] or m*rmul+radd
// BMODE 0: B f32 [K][ldb] row-major (cvt+transpose in staging)
// BMODE 1: B bf16 packed [K/32][ldb][32] (fragment-order; pure 16B copies)
// OUTM: bit0 -> f32 out, bit1 -> bf16 out
// SPLITK: K = per-chunk; blockIdx.z selects chunk; partial at Cf + z*M*ldc
// SWZ: bijective XCD swizzle so consecutive work ids share an XCD L2
// ---------------------------------------------------------------------------
template<int BM, int BN, int TH, int WY, int WX, bool ABF16, bool GATHER,
         int BMODE, bool RELU, int OUTM, bool SPLITK, bool SWZ>
__global__ __launch_bounds__(TH)
void gemm_k(const void* __restrict__ Av, int lda, int rmul, int radd,
            const int* __restrict__ gidx,
            const void* __restrict__ Bp, int ldb,
            const float* __restrict__ bias,
            float* __restrict__ Cf, unsigned short* __restrict__ Cb, int ldc,
            int M, int N, int K)
{
  constexpr int WM = BM / WY, WN = BN / WX, FM = WM / 16, FN = WN / 16;
  __shared__ unsigned short As[2][BM][LR];
  __shared__ unsigned short Bs[2][BN][LR];
  const int tid = threadIdx.x;
  const int lane = tid & 63;
  const int wid = tid >> 6;
  const int wy = wid / WX, wx = wid % WX;
  int bx = blockIdx.x, by = blockIdx.y;
  if constexpr (SWZ) {
    const int gx = gridDim.x, total = gx * gridDim.y;
    const int bid = by * gx + bx;
    const int q = total >> 3, r = total & 7;
    const int xcd = bid & 7, idx = bid >> 3;
    const int j = (xcd < r ? xcd * (q + 1) : r * (q + 1) + (xcd - r) * q) + idx;
    bx = j % gx; by = j / gx;
  }
  const long m0 = (long)bx * BM;
  const int n0 = by * BN;
  const int kbeg = SPLITK ? blockIdx.z * K : 0;
  if constexpr (SPLITK) Cf += (long)blockIdx.z * M * ldc;

  f32x4 acc[FM][FN];
#pragma unroll
  for (int i = 0; i < FM; ++i)
#pragma unroll
    for (int j = 0; j < FN; ++j) acc[i][j] = (f32x4)0.f;

  const int nsteps = K / KS;

  auto stageA = [&](int ks, int buf) {
    const int k0 = kbeg + ks * KS;
    if constexpr (!ABF16) {
      const float* A = (const float*)Av;
#pragma unroll
      for (int p = 0; p < BM / (TH / 8); ++p) {
        const int r = p * (TH / 8) + (tid >> 3);
        const int kq = tid & 7;
        long ar = GATHER ? (long)gidx[m0 + r] : ((m0 + r) * (long)rmul + radd);
        f32x4 v = *(const f32x4*)(A + ar * lda + k0 + kq * 4);
        u16x4 o;
        o[0] = f2bf(v[0]); o[1] = f2bf(v[1]); o[2] = f2bf(v[2]); o[3] = f2bf(v[3]);
        *(u16x4*)(&As[buf][r][kq * 4]) = o;
      }
    } else {
      const unsigned short* A = (const unsigned short*)Av;
#pragma unroll
      for (int p = 0; p < BM / (TH / 4); ++p) {
        const int r = p * (TH / 4) + (tid >> 2);
        const int cq = tid & 3;
        long ar = (m0 + r) * (long)rmul + radd;
        u32x4 v = *(const u32x4*)(A + ar * lda + k0 + cq * 8);
        *(u32x4*)(&As[buf][r][cq * 8]) = v;
      }
    }
  };

  auto stageB = [&](int ks, int buf) {
    if constexpr (BMODE == 0) {
      const float* B = (const float*)Bp;
      const int k0 = kbeg + ks * KS;
      constexpr int NC = BN / 4;
#pragma unroll
      for (int p = 0; p < (KS * NC) / TH; ++p) {
        const int n4 = tid % NC;
        const int k = p * (TH / NC) + tid / NC;
        const int c0 = n0 + n4 * 4;
        f32x4 v;
        if (c0 + 3 < N) {
          v = *(const f32x4*)(B + (long)(k0 + k) * ldb + c0);
        } else {
#pragma unroll
          for (int e = 0; e < 4; ++e)
            v[e] = (c0 + e < N) ? B[(long)(k0 + k) * ldb + c0 + e] : 0.f;
        }
        Bs[buf][n4 * 4 + 0][k] = f2bf(v[0]);
        Bs[buf][n4 * 4 + 1][k] = f2bf(v[1]);
        Bs[buf][n4 * 4 + 2][k] = f2bf(v[2]);
        Bs[buf][n4 * 4 + 3][k] = f2bf(v[3]);
      }
    } else {
      const unsigned short* B = (const unsigned short*)Bp;
      const int ksg = (kbeg / KS) + ks;
#pragma unroll
      for (int p = 0; p < (BN * 4) / TH; ++p) {
        const int cc = p * (TH / 4) + (tid >> 2);
        const int q = tid & 3;
        u32x4 v = *(const u32x4*)(B + ((long)ksg * ldb + n0 + cc) * 32 + q * 8);
        *(u32x4*)(&Bs[buf][cc][q * 8]) = v;
      }
    }
  };

  stageA(0, 0); stageB(0, 0);

  for (int ks = 0; ks < nsteps; ++ks) {
    __syncthreads();
    if (ks + 1 < nsteps) { stageA(ks + 1, (ks + 1) & 1); stageB(ks + 1, (ks + 1) & 1); }
    const int buf = ks & 1;
    short8 ar[FM], br[FN];
#pragma unroll
    for (int fm = 0; fm < FM; ++fm)
      ar[fm] = *(const short8*)(&As[buf][wy * WM + fm * 16 + (lane & 15)][(lane >> 4) * 8]);
#pragma unroll
    for (int fn = 0; fn < FN; ++fn)
      br[fn] = *(const short8*)(&Bs[buf][wx * WN + fn * 16 + (lane & 15)][(lane >> 4) * 8]);
#pragma unroll
    for (int fm = 0; fm < FM; ++fm)
#pragma unroll
      for (int fn = 0; fn < FN; ++fn)
        acc[fm][fn] = __builtin_amdgcn_mfma_f32_16x16x32_bf16(ar[fm], br[fn], acc[fm][fn], 0, 0, 0);
  }

#pragma unroll
  for (int fm = 0; fm < FM; ++fm) {
    const long row0 = m0 + wy * WM + fm * 16 + ((lane >> 4) << 2);
#pragma unroll
    for (int fn = 0; fn < FN; ++fn) {
      const int col = n0 + wx * WN + fn * 16 + (lane & 15);
      if (col >= N) continue;
      const float bv = bias ? bias[col] : 0.f;
#pragma unroll
      for (int j = 0; j < 4; ++j) {
        float v = acc[fm][fn][j] + bv;
        if constexpr (RELU) v = fmaxf(v, 0.f);
        const long r = row0 + j;
        if constexpr (OUTM & 1) Cf[r * ldc + col] = v;
        if constexpr (OUTM & 2) Cb[r * ldc + col] = f2bf(v);
      }
    }
  }
}

// ---------------------------------------------------------------------------
// packB: f32 [K][Nsrc] row-major -> bf16 packed [K/32][Ndst][32], zero-pad cols
// ---------------------------------------------------------------------------
__global__ __launch_bounds__(256)
void packB_k(const float* __restrict__ src, unsigned short* __restrict__ dst,
             int Nsrc, int Ndst)
{
  const int t = blockIdx.x * 256 + threadIdx.x;
  const int ks = t / Ndst, n = t - ks * Ndst;
  unsigned short buf[32];
#pragma unroll
  for (int kk = 0; kk < 32; ++kk)
    buf[kk] = (n < Nsrc) ? f2bf(src[(long)(ks * 32 + kk) * Nsrc + n]) : (unsigned short)0;
#pragma unroll
  for (int q = 0; q < 4; ++q)
    *(u32x4*)(dst + ((long)ks * Ndst + n) * 32 + q * 8) = *(const u32x4*)(buf + q * 8);
}

// ---------------------------------------------------------------------------
// Fused alpha kernel v2: per block = 64 rows x 128 cols (z-half) of one head.
//   q2 tile via MFMA (K=256), q1 staged in LDS, sigmoid via native rcp,
//   partial alpha (sum over this half's 128 cols) -> alpha[z][b][n][l]
// ---------------------------------------------------------------------------
__global__ __launch_bounds__(256)
void alpha_k(const unsigned short* __restrict__ fea,   // [25600][256] bf16
             const unsigned short* __restrict__ w2t,   // [8][256(d)][256(h)] bf16
             const float* __restrict__ q1buf,          // [512][2048]
             const float* __restrict__ vw,             // [8][256]
             float* __restrict__ alpha)                // [2][512][8][50]
{
  __shared__ unsigned short As[2][64][LR];
  __shared__ unsigned short Bs[2][128][LR];
  __shared__ float vws[128];
  __shared__ float q1s[3][128];
  __shared__ float red[2][64];
  const int tid = threadIdx.x;
  const int lane = tid & 63;
  const int w = tid >> 6;
  const int wy = w >> 1, wx = w & 1;
  const int m0 = blockIdx.x * 64;
  const int n = blockIdx.y;
  const int z = blockIdx.z;
  const int c0g = z * 128;            // global col base within head
  const int b0 = m0 / 50;

  if (tid < 128) vws[tid] = vw[n * 256 + c0g + tid];
  for (int i = tid; i < 384; i += 256) {
    const int bi = i >> 7, cc = i & 127;
    const int bb = min(b0 + bi, 511);
    q1s[bi][cc] = q1buf[(long)bb * 2048 + n * 256 + c0g + cc];
  }

  f32x4 acc[2][4];
#pragma unroll
  for (int i = 0; i < 2; ++i)
#pragma unroll
    for (int j = 0; j < 4; ++j) acc[i][j] = (f32x4)0.f;

  auto stageA = [&](int ks, int buf) {
    const int k0 = ks * KS;
    const int r = tid >> 2, cq = tid & 3;
    u32x4 v = *(const u32x4*)(fea + (long)(m0 + r) * 256 + k0 + cq * 8);
    *(u32x4*)(&As[buf][r][cq * 8]) = v;
  };
  auto stageB = [&](int ks, int buf) {
    const int k0 = ks * KS;
#pragma unroll
    for (int p = 0; p < 2; ++p) {
      const int r = p * 64 + (tid >> 2), cq = tid & 3;
      u32x4 v = *(const u32x4*)(w2t + ((long)(n * 256 + c0g + r)) * 256 + k0 + cq * 8);
      *(u32x4*)(&Bs[buf][r][cq * 8]) = v;
    }
  };

  stageA(0, 0); stageB(0, 0);
  for (int ks = 0; ks < 8; ++ks) {
    __syncthreads();
    if (ks < 7) { stageA(ks + 1, (ks + 1) & 1); stageB(ks + 1, (ks + 1) & 1); }
    const int buf = ks & 1;
    short8 ar[2], br[4];
#pragma unroll
    for (int fm = 0; fm < 2; ++fm)
      ar[fm] = *(const short8*)(&As[buf][wy * 32 + fm * 16 + (lane & 15)][(lane >> 4) * 8]);
#pragma unroll
    for (int fn = 0; fn < 4; ++fn)
      br[fn] = *(const short8*)(&Bs[buf][wx * 64 + fn * 16 + (lane & 15)][(lane >> 4) * 8]);
#pragma unroll
    for (int fm = 0; fm < 2; ++fm)
#pragma unroll
      for (int fn = 0; fn < 4; ++fn)
        acc[fm][fn] = __builtin_amdgcn_mfma_f32_16x16x32_bf16(ar[fm], br[fn], acc[fm][fn], 0, 0, 0);
  }

  // epilogue: sigmoid + dot v_w over this block's 128 cols
  const int g = lane >> 4, c = lane & 15;
  float part[2][4];
#pragma unroll
  for (int fm = 0; fm < 2; ++fm) {
#pragma unroll
    for (int j = 0; j < 4; ++j) {
      const int m = m0 + wy * 32 + fm * 16 + g * 4 + j;
      const int bi = m / 50 - b0;
      float p = 0.f;
#pragma unroll
      for (int fn = 0; fn < 4; ++fn) {
        const int colL = wx * 64 + fn * 16 + c;
        const float q = acc[fm][fn][j] + q1s[bi][colL];
        const float e = __expf(-q);
        p += vws[colL] * __builtin_amdgcn_rcpf(1.f + e);
      }
      part[fm][j] = p;
    }
  }
#pragma unroll
  for (int fm = 0; fm < 2; ++fm)
#pragma unroll
    for (int j = 0; j < 4; ++j)
#pragma unroll
      for (int off = 1; off < 16; off <<= 1)
        part[fm][j] += __shfl_xor(part[fm][j], off);
  if (c == 0) {
#pragma unroll
    for (int fm = 0; fm < 2; ++fm)
#pragma unroll
      for (int j = 0; j < 4; ++j)
        red[wx][wy * 32 + fm * 16 + g * 4 + j] = part[fm][j];
  }
  __syncthreads();
  if (tid < 64) {
    const float s = red[0][tid] + red[1][tid];
    const int m = m0 + tid;
    const int b = m / 50, l = m - b * 50;
    alpha[(((long)z * 512 + b) * 8 + n) * 50 + l] = s;
  }
}

// ---------------------------------------------------------------------------
// c_final assembly, compact layout [b][2304]: n*256+h = a_n, 2048+h = ht
// (sums the two z-halves of alpha)
// ---------------------------------------------------------------------------
__global__ __launch_bounds__(256)
void cfinal_k(const unsigned short* __restrict__ fea,
              const float* __restrict__ alpha,        // [2][512][8][50]
              const int* __restrict__ seq,
              unsigned short* __restrict__ cfin)
{
  __shared__ unsigned short feas[50][256];
  __shared__ float al[8][50];
  const int b = blockIdx.x, t = threadIdx.x;
#pragma unroll 1
  for (int l = 0; l < 50; ++l)
    feas[l][t] = fea[((long)b * 50 + l) * 256 + t];
  for (int i = t; i < 400; i += 256) {
    const int nn = i / 50, l = i - nn * 50;
    const float mk = (seq[b * 50 + l] > 0) ? 1.f : 0.f;
    const long idx = ((long)b * 8 + nn) * 50 + l;
    al[nn][l] = (alpha[idx] + alpha[204800 + idx]) * mk;
  }
  __syncthreads();
#pragma unroll 1
  for (int nn = 0; nn < 8; ++nn) {
    float acc = 0.f;
#pragma unroll
    for (int l = 0; l < 50; ++l) acc += al[nn][l] * bf2f(feas[l][t]);
    cfin[(long)b * 2304 + nn * 256 + t] = f2bf(acc);
  }
  cfin[(long)b * 2304 + 2048 + t] = feas[49][t];
}

// ---------------------------------------------------------------------------
// lin0 split-K reduce: sum 8 partials + bias + relu -> f32 + bf16
// ---------------------------------------------------------------------------
__global__ __launch_bounds__(256)
void lin0red_k(const float* __restrict__ part, const float* __restrict__ bias,
               float* __restrict__ cf, unsigned short* __restrict__ cb)
{
  const int e = blockIdx.x * 256 + threadIdx.x;
  float s = bias[e & 255];
#pragma unroll
  for (int z = 0; z < 8; ++z) s += part[z * 131072 + e];
  s = fmaxf(s, 0.f);
  cf[e] = s;
  cb[e] = f2bf(s);
}

// ---------------------------------------------------------------------------
// Fused BatchNorm: sums 4 split-K partials, stats + apply + relu [+ residual]
// (biases omitted: BN is shift-invariant, so l?_b cancel exactly)
// ---------------------------------------------------------------------------
template<bool LAST>
__global__ __launch_bounds__(256)
void bn_k(const float* __restrict__ y, const float* __restrict__ g,
          const float* __restrict__ be, const float* __restrict__ cres,
          unsigned short* __restrict__ out)
{
  const int t = threadIdx.x;
  const int col = blockIdx.x * 8 + (t & 7);
  const int rg = t >> 3;
  float v[16];
  float s = 0.f, q = 0.f;
#pragma unroll
  for (int i = 0; i < 16; ++i) {
    const int off = (rg + i * 32) * 256 + col;
    float x = y[off] + y[131072 + off] + y[262144 + off] + y[393216 + off];
    v[i] = x;
    s += x; q += x * x;
  }
  for (int off = 8; off < 64; off <<= 1) { s += __shfl_xor(s, off); q += __shfl_xor(q, off); }
  __shared__ float ps[4][8], pq[4][8], mm[8], rr[8];
  if ((t & 63) < 8) { ps[t >> 6][t & 7] = s; pq[t >> 6][t & 7] = q; }
  __syncthreads();
  if (t < 8) {
    const float S = ps[0][t] + ps[1][t] + ps[2][t] + ps[3][t];
    const float Q = pq[0][t] + pq[1][t] + pq[2][t] + pq[3][t];
    const float m = S * (1.f / 512.f);
    const float var = Q * (1.f / 512.f) - m * m;
    mm[t] = m;
    rr[t] = rsqrtf(var + 1e-5f);
  }
  __syncthreads();
  const float m = mm[t & 7], r = rr[t & 7], gg = g[col], bb = be[col];
#pragma unroll
  for (int i = 0; i < 16; ++i) {
    float h = (v[i] - m) * r * gg + bb;
    h = fmaxf(h, 0.f);
    if constexpr (LAST) h += cres[(rg + i * 32) * 256 + col];
    out[(rg + i * 32) * 256 + col] = f2bf(h);
  }
}

// ---------------------------------------------------------------------------
// prepack: w1t[h][n*256+d]=w1_w[n][h][d]; w2t[n][d][h]=bf16(w2_w[n][h][d]);
// bias12 = w1_b + w2_b
// ---------------------------------------------------------------------------
__global__ __launch_bounds__(256)
void prepack_k(const float* __restrict__ w1w, const float* __restrict__ w1b,
               const float* __restrict__ w2w, const float* __restrict__ w2b,
               float* __restrict__ w1t, float* __restrict__ bias12,
               unsigned short* __restrict__ w2t)
{
  const int tid = blockIdx.x * 256 + threadIdx.x;
  if (tid < 524288) {
    const int nn = tid >> 16, rem = tid & 65535, h = rem >> 8, d = rem & 255;
    w1t[h * 2048 + nn * 256 + d] = w1w[tid];
    w2t[((long)(nn * 256 + d)) * 256 + h] = f2bf(w2w[tid]);
  }
  if (tid < 2048) bias12[tid] = w1b[tid] + w2b[tid];
}

// wcat [2304][256]: rows n*256+h = lin0_w[n*512+h]; rows 2048+h = sum_n lin0_w[n*512+256+h]
__global__ __launch_bounds__(256)
void prepack2_k(const float* __restrict__ lin0w, float* __restrict__ wcat)
{
  const int e = blockIdx.x * 256 + threadIdx.x;   // 0..589823
  const int h2 = e >> 8, d = e & 255;
  float v;
  if (h2 < 2048) {
    const int n = h2 >> 8, h = h2 & 255;
    v = lin0w[((n * 512 + h) << 8) + d];
  } else {
    const int h = h2 - 2048;
    v = 0.f;
#pragma unroll
    for (int n = 0; n < 8; ++n) v += lin0w[((n * 512 + 256 + h) << 8) + d];
  }
  wcat[e] = v;
}

// ---------------------------------------------------------------------------
extern "C" void kernel_launch(void* const* d_in, const int* in_sizes, int n_in,
                              void* d_out, int out_size, void* d_ws, size_t ws_size,
                              hipStream_t stream)
{
  const int*   seq    = (const int*)  d_in[0];
  const float* topic  = (const float*)d_in[1];
  const float* dr_w   = (const float*)d_in[2];
  const float* dr_b   = (const float*)d_in[3];
  const float* w1_w   = (const float*)d_in[4];
  const float* w1_b   = (const float*)d_in[5];
  const float* w2_w   = (const float*)d_in[6];
  const float* w2_b   = (const float*)d_in[7];
  const float* v_w    = (const float*)d_in[8];
  const float* lin0_w = (const float*)d_in[9];
  const float* lin0_b = (const float*)d_in[10];
  const float* l1_w   = (const float*)d_in[11];
  const float* g1     = (const float*)d_in[13];
  const float* be1    = (const float*)d_in[14];
  const float* l2_w   = (const float*)d_in[15];
  const float* g2     = (const float*)d_in[17];
  const float* be2    = (const float*)d_in[18];
  const float* l3_w   = (const float*)d_in[19];
  const float* g3     = (const float*)d_in[21];
  const float* be3    = (const float*)d_in[22];
  const float* out_w  = (const float*)d_in[23];
  float* outp = (float*)d_out;

  char* ws = (char*)d_ws;
  size_t off = 0;
  auto alloc = [&](size_t bytes) -> void* {
    void* p = ws + off;
    off += (bytes + 255) & ~(size_t)255;
    return p;
  };
  unsigned short* fea    = (unsigned short*)alloc(25600ull * 256 * 2);
  unsigned short* w2t    = (unsigned short*)alloc(8ull * 256 * 256 * 2);
  float* w1t             = (float*)alloc(256ull * 2048 * 4);
  float* bias12          = (float*)alloc(2048ull * 4);
  float* q1buf           = (float*)alloc(512ull * 2048 * 4);
  float* alphab          = (float*)alloc(2ull * 512 * 8 * 50 * 4);
  unsigned short* cfin   = (unsigned short*)alloc(512ull * 2304 * 2);
  float* wcat            = (float*)alloc(2304ull * 256 * 4);
  float* part            = (float*)alloc(8ull * 512 * 256 * 4);
  float* c_f32           = (float*)alloc(512ull * 256 * 4);
  unsigned short* c_bf   = (unsigned short*)alloc(512ull * 256 * 2);
  unsigned short* h_bf   = (unsigned short*)alloc(512ull * 256 * 2);
  unsigned short* hc_bf  = (unsigned short*)alloc(512ull * 256 * 2);
  unsigned short* drwp   = (unsigned short*)alloc(16ull * 256 * 32 * 2);      // dr_w packed
  unsigned short* wpad   = (unsigned short*)alloc(8ull * 50048 * 32 * 2);     // out_w packed

  // 0) weight prepack
  hipLaunchKernelGGL(prepack_k, dim3(2048), dim3(256), 0, stream,
                     w1_w, w1_b, w2_w, w2_b, w1t, bias12, w2t);
  hipLaunchKernelGGL(prepack2_k, dim3(2304), dim3(256), 0, stream, lin0_w, wcat);
  hipLaunchKernelGGL(packB_k, dim3(16), dim3(256), 0, stream, dr_w, drwp, 256, 256);
  hipLaunchKernelGGL(packB_k, dim3(1564), dim3(256), 0, stream, out_w, wpad, 49999, 50048);

  // 1) fea = relu(topic[seq] @ dr_w + dr_b) -> bf16 [25600][256]
  hipLaunchKernelGGL((gemm_k<64,256,256,1,4, false,true, 1, true, 2, false,false>),
                     dim3(400, 1), dim3(256), 0, stream,
                     (const void*)topic, 512, 1, 0, seq, (const void*)drwp, 256, dr_b,
                     (float*)nullptr, fea, 256, 25600, 256, 512);

  // 2) q1 = ht @ w1t + (w1_b + w2_b)  -> f32 [512][2048]
  hipLaunchKernelGGL((gemm_k<64,64,256,2,2, true,false, 0, false, 1, false,false>),
                     dim3(8, 32), dim3(256), 0, stream,
                     (const void*)fea, 256, 50, 49, (const int*)nullptr,
                     (const void*)w1t, 2048, bias12,
                     q1buf, (unsigned short*)nullptr, 2048, 512, 2048, 256);

  // 3) fused q2 + sigmoid + dot(v_w) -> partial alpha [2][512][8][50]
  hipLaunchKernelGGL(alpha_k, dim3(400, 8, 2), dim3(256), 0, stream,
                     fea, w2t, q1buf, v_w, alphab);

  // 4) c_final assembly -> bf16 [512][2304]
  hipLaunchKernelGGL(cfinal_k, dim3(512), dim3(256), 0, stream, fea, alphab, seq, cfin);

  // 5) c = relu(cfin @ wcat + lin0_b): split-K=8 partials then reduce
  hipLaunchKernelGGL((gemm_k<64,64,256,2,2, true,false, 0, false, 1, true,false>),
                     dim3(8, 4, 8), dim3(256), 0, stream,
                     (const void*)cfin, 2304, 1, 0, (const int*)nullptr,
                     (const void*)wcat, 256, (const float*)nullptr,
                     part, (unsigned short*)nullptr, 256, 512, 256, 288);
  hipLaunchKernelGGL(lin0red_k, dim3(512), dim3(256), 0, stream, part, lin0_b, c_f32, c_bf);

  // 6-8) l1..l3: split-K=4 GEMM (no bias; BN cancels it) + fused BN
  hipLaunchKernelGGL((gemm_k<64,64,256,2,2, true,false, 0, false, 1, true,false>),
                     dim3(8, 4, 4), dim3(256), 0, stream,
                     (const void*)c_bf, 256, 1, 0, (const int*)nullptr,
                     (const void*)l1_w, 256, (const float*)nullptr,
                     part, (unsigned short*)nullptr, 256, 512, 256, 64);
  hipLaunchKernelGGL((bn_k<false>), dim3(32), dim3(256), 0, stream,
                     part, g1, be1, (const float*)nullptr, h_bf);

  hipLaunchKernelGGL((gemm_k<64,64,256,2,2, true,false, 0, false, 1, true,false>),
                     dim3(8, 4, 4), dim3(256), 0, stream,
                     (const void*)h_bf, 256, 1, 0, (const int*)nullptr,
                     (const void*)l2_w, 256, (const float*)nullptr,
                     part, (unsigned short*)nullptr, 256, 512, 256, 64);
  hipLaunchKernelGGL((bn_k<false>), dim3(32), dim3(256), 0, stream,
                     part, g2, be2, (const float*)nullptr, h_bf);

  hipLaunchKernelGGL((gemm_k<64,64,256,2,2, true,false, 0, false, 1, true,false>),
                     dim3(8, 4, 4), dim3(256), 0, stream,
                     (const void*)h_bf, 256, 1, 0, (const int*)nullptr,
                     (const void*)l3_w, 256, (const float*)nullptr,
                     part, (unsigned short*)nullptr, 256, 512, 256, 64);
  hipLaunchKernelGGL((bn_k<true>), dim3(32), dim3(256), 0, stream,
                     part, g3, be3, c_f32, hc_bf);

  // 9) out = (h + c) @ out_w : packed-bf16 B + XCD swizzle
  hipLaunchKernelGGL((gemm_k<128,128,256,2,2, true,false, 1, false, 1, false,true>),
                     dim3(4, 391), dim3(256), 0, stream,
                     (const void*)hc_bf, 256, 1, 0, (const int*)nullptr,
                     (const void*)wpad, 50048, (const float*)nullptr,
                     outp, (unsigned short*)nullptr, 49999, 512, 49999, 256);

  (void)in_sizes; (void)n_in; (void)out_size; (void)ws_size;
}